// Round 10
// baseline (281.962 us; speedup 1.0000x reference)
//
#include <hip/hip_runtime.h>
#include <hip/hip_fp16.h>

#define EPSV 1e-5f
#define PST 2048
#define GRID_GEMM 1563
#define GRID_MIX  2048
#define GRID_ELT  2048

typedef _Float16 h2_t  __attribute__((ext_vector_type(2)));  // packed arithmetic
typedef __fp16   fp16x2 __attribute__((ext_vector_type(2))); // builtin interop
typedef _Float16 f16x4 __attribute__((ext_vector_type(4)));  // MFMA K=16 A/B frag
typedef _Float16 f16x8 __attribute__((ext_vector_type(8)));  // MFMA K=32 A/B frag
typedef float    f32x4 __attribute__((ext_vector_type(4)));  // MFMA C/D frag
typedef unsigned short u16;

__device__ __forceinline__ float frelu(float x) { return fmaxf(x, 0.f); }

__device__ __forceinline__ unsigned int pkrtz(float lo, float hi) {
  fp16x2 h = __builtin_amdgcn_cvt_pkrtz(lo, hi);
  return __builtin_bit_cast(unsigned int, h);
}
__device__ __forceinline__ u16 f16b(float x) {
  return (u16)(pkrtz(x, 0.f) & 0xffffu);
}
__device__ __forceinline__ f16x8 mk8(unsigned a, unsigned b, unsigned c, unsigned d) {
  uint4 u; u.x = a; u.y = b; u.z = c; u.w = d;
  return __builtin_bit_cast(f16x8, u);
}
__device__ __forceinline__ f16x4 mk4(unsigned a, unsigned b) {
  uint2 u; u.x = a; u.y = b;
  return __builtin_bit_cast(f16x4, u);
}
__device__ __forceinline__ f32x4 mfma16(f16x8 a, f16x8 b, f32x4 c) {
  return __builtin_amdgcn_mfma_f32_16x16x32_f16(a, b, c, 0, 0, 0);
}
__device__ __forceinline__ f32x4 mfma16k16(f16x4 a, f16x4 b, f32x4 c) {
  return __builtin_amdgcn_mfma_f32_16x16x16f16(a, b, c, 0, 0, 0);
}
// packed f16 relu via sign-bit masking
__device__ __forceinline__ unsigned relu2(unsigned u) {
  const unsigned m = ((u & 0x80008000u) >> 15) * 0xFFFFu;
  return u & ~m;
}

// ---------------------------------------------------------------------------
// MFMA f16 GEMM: out16[N,64](f16) = preop(in) @ W.
// MODE0 additionally: last block packs ww/wp2/wp1 fragment buffers (then exits).
template<int MODE, bool INF16>
__global__ __launch_bounds__(256, 4) void gemm_mfma_k(
    const void* __restrict__ in, const float* __restrict__ W,
    const float* __restrict__ Ww, const float* __restrict__ ss,
    u16* __restrict__ out16, u16* __restrict__ outw16,
    float* __restrict__ partials, int N,
    const float* __restrict__ Wp2, const float* __restrict__ Wp1,
    uint4* __restrict__ wwf, uint4* __restrict__ wp2f, uint4* __restrict__ w1f)
{
  __shared__ float red[512];
  __shared__ u16 xh[4][16*72];
  const int t = threadIdx.x, lane = t & 63, w = t >> 6;
  const int r16 = lane & 15, q = lane >> 4;

  if (MODE == 0 && blockIdx.x == GRID_GEMM) {
    float* wwl = (float*)&xh[0][0];   // 512 floats
    {
      const int a = t >> 2, qq = t & 3;
      float acc[8] = {0,0,0,0,0,0,0,0};
#pragma unroll
      for (int cc = 0; cc < 16; ++cc) {
        const int c = qq*16 + cc;
        const float wv = Wp2[a*64 + c];
#pragma unroll
        for (int g = 0; g < 8; ++g) acc[g] = fmaf(wv, Ww[c*8 + g], acc[g]);
      }
#pragma unroll
      for (int g = 0; g < 8; ++g) {
        acc[g] += __shfl_xor(acc[g], 1);
        acc[g] += __shfl_xor(acc[g], 2);
      }
      if (qq == 0) {
#pragma unroll
        for (int g = 0; g < 8; ++g) wwl[a*8 + g] = acc[g];
      }
    }
    __syncthreads();
    if (t < 128) {
      const int h = t >> 6, l = t & 63, rr = l & 15, qq = l >> 4;
      uint4 u = {0,0,0,0};
      if (rr < 8) {
        u.x = pkrtz(wwl[(32*h+8*qq+0)*8 + rr], wwl[(32*h+8*qq+1)*8 + rr]);
        u.y = pkrtz(wwl[(32*h+8*qq+2)*8 + rr], wwl[(32*h+8*qq+3)*8 + rr]);
        u.z = pkrtz(wwl[(32*h+8*qq+4)*8 + rr], wwl[(32*h+8*qq+5)*8 + rr]);
        u.w = pkrtz(wwl[(32*h+8*qq+6)*8 + rr], wwl[(32*h+8*qq+7)*8 + rr]);
      }
      wwf[t] = u;
    }
    for (int e = t; e < 512; e += 256) {
      const int tt = e >> 7, h = (e >> 6) & 1, l = e & 63;
      const int c = 16*tt + (l & 15), qq = l >> 4;
      const int d0 = 32*h + 8*qq;
      uint4 u;
      u.x = pkrtz(Wp2[(d0+0)*64 + c], Wp2[(d0+1)*64 + c]);
      u.y = pkrtz(Wp2[(d0+2)*64 + c], Wp2[(d0+3)*64 + c]);
      u.z = pkrtz(Wp2[(d0+4)*64 + c], Wp2[(d0+5)*64 + c]);
      u.w = pkrtz(Wp2[(d0+6)*64 + c], Wp2[(d0+7)*64 + c]);
      wp2f[e] = u;
    }
    for (int e = t; e < 384; e += 256) {
      const int r = e >> 7, h = (e >> 6) & 1, l = e & 63, qq = l >> 4;
      const int d0 = 32*h + 8*qq;
      uint4 u;
      u.x = pkrtz(Wp1[r*64 + d0+0], Wp1[r*64 + d0+1]);
      u.y = pkrtz(Wp1[r*64 + d0+2], Wp1[r*64 + d0+3]);
      u.z = pkrtz(Wp1[r*64 + d0+4], Wp1[r*64 + d0+5]);
      u.w = pkrtz(Wp1[r*64 + d0+6], Wp1[r*64 + d0+7]);
      w1f[e] = u;
    }
    return;
  }

  u16* const xw = &xh[w][0];
  f16x8 bw[2][4];
#pragma unroll
  for (int kb = 0; kb < 2; ++kb) {
#pragma unroll
    for (int tt = 0; tt < 4; ++tt) {
      const int kbase = 32*kb + 8*q;
      const int cc = 16*tt + r16;
      unsigned u0 = pkrtz(W[(kbase+0)*64 + cc], W[(kbase+1)*64 + cc]);
      unsigned u1 = pkrtz(W[(kbase+2)*64 + cc], W[(kbase+3)*64 + cc]);
      unsigned u2 = pkrtz(W[(kbase+4)*64 + cc], W[(kbase+5)*64 + cc]);
      unsigned u3 = pkrtz(W[(kbase+6)*64 + cc], W[(kbase+7)*64 + cc]);
      bw[kb][tt] = mk8(u0, u1, u2, u3);
    }
  }
  f16x8 bg[2];
  if (MODE == 1) {
#pragma unroll
    for (int kb = 0; kb < 2; ++kb) {
      const int kbase = 32*kb + 8*q;
      unsigned u[4];
#pragma unroll
      for (int mm = 0; mm < 4; ++mm) {
        float g0 = (r16 < 8) ? Ww[(kbase + 2*mm    )*8 + r16] : 0.f;
        float g1 = (r16 < 8) ? Ww[(kbase + 2*mm + 1)*8 + r16] : 0.f;
        u[mm] = pkrtz(g0, g1);
      }
      bg[kb] = mk8(u[0], u[1], u[2], u[3]);
    }
  }
  float sc4[4], sh4[4];
  if (MODE != 0) {
#pragma unroll
    for (int j = 0; j < 4; ++j) {
      sc4[j] = ss[4*r16 + j];
      sh4[j] = ss[64 + 4*r16 + j];
    }
  }

  float S4[4] = {0,0,0,0}, Q4[4] = {0,0,0,0};
  const int ntiles = (N + 15) >> 4;
  for (int tile = blockIdx.x*4 + w; tile < ntiles; tile += GRID_GEMM*4) {
    const int r0 = tile << 4;
    const bool full = (r0 + 16 <= N);
#pragma unroll
    for (int i = 0; i < 4; ++i) {
      const int row = q + 4*i;
      float4 xv = {0.f, 0.f, 0.f, 0.f};
      const bool rok = full || (r0 + row < N);
      if (rok) {
        if constexpr (INF16) {
          const uint2 u = *(const uint2*)((const u16*)in + (size_t)(r0 + row)*64 + 4*r16);
          const h2_t lo = __builtin_bit_cast(h2_t, u.x);
          const h2_t hi = __builtin_bit_cast(h2_t, u.y);
          xv.x = (float)lo[0]; xv.y = (float)lo[1];
          xv.z = (float)hi[0]; xv.w = (float)hi[1];
        } else {
          xv = *(const float4*)((const float*)in + (size_t)(r0 + row)*64 + 4*r16);
        }
      }
      if (MODE != 0) {
        xv.x = frelu(fmaf(xv.x, sc4[0], sh4[0]));
        xv.y = frelu(fmaf(xv.y, sc4[1], sh4[1]));
        xv.z = frelu(fmaf(xv.z, sc4[2], sh4[2]));
        xv.w = frelu(fmaf(xv.w, sc4[3], sh4[3]));
        if (!rok) { xv.x = 0.f; xv.y = 0.f; xv.z = 0.f; xv.w = 0.f; }
      }
      uint2 u2v; u2v.x = pkrtz(xv.x, xv.y); u2v.y = pkrtz(xv.z, xv.w);
      *(uint2*)(xw + row*72 + 4*r16) = u2v;
    }
    const f16x8 a0 = __builtin_bit_cast(f16x8, *(const uint4*)(xw + r16*72 + 8*q));
    const f16x8 a1 = __builtin_bit_cast(f16x8, *(const uint4*)(xw + r16*72 + 8*q + 32));
    f32x4 acc[4];
#pragma unroll
    for (int tt = 0; tt < 4; ++tt) {
      f32x4 z = {0.f, 0.f, 0.f, 0.f};
      z = mfma16(a0, bw[0][tt], z);
      acc[tt] = mfma16(a1, bw[1][tt], z);
    }
#pragma unroll
    for (int tt = 0; tt < 4; ++tt) {
#pragma unroll
      for (int j = 0; j < 4; ++j) {
        if (full || (r0 + 4*q + j < N))
          out16[(size_t)(r0 + 4*q + j)*64 + 16*tt + r16] = f16b(acc[tt][j]);
      }
      if (MODE != 1) {
        S4[tt] += acc[tt][0] + acc[tt][1] + acc[tt][2] + acc[tt][3];
        Q4[tt] = fmaf(acc[tt][0], acc[tt][0], Q4[tt]);
        Q4[tt] = fmaf(acc[tt][1], acc[tt][1], Q4[tt]);
        Q4[tt] = fmaf(acc[tt][2], acc[tt][2], Q4[tt]);
        Q4[tt] = fmaf(acc[tt][3], acc[tt][3], Q4[tt]);
      }
    }
    if (MODE == 1) {
      f32x4 accw = {0.f, 0.f, 0.f, 0.f};
      accw = mfma16(a0, bg[0], accw);
      accw = mfma16(a1, bg[1], accw);
      if (r16 < 8) {
#pragma unroll
        for (int j = 0; j < 4; ++j) {
          if (full || (r0 + 4*q + j < N))
            outw16[(size_t)(r0 + 4*q + j)*8 + r16] = f16b(accw[j]);
        }
      }
    }
  }
  if (MODE != 1) {
#pragma unroll
    for (int tt = 0; tt < 4; ++tt) {
      S4[tt] += __shfl_xor(S4[tt], 16); S4[tt] += __shfl_xor(S4[tt], 32);
      Q4[tt] += __shfl_xor(Q4[tt], 16); Q4[tt] += __shfl_xor(Q4[tt], 32);
    }
    if (lane < 16) {
#pragma unroll
      for (int tt = 0; tt < 4; ++tt) {
        red[w*128 + tt*16 + lane]      = S4[tt];
        red[w*128 + 64 + tt*16 + lane] = Q4[tt];
      }
    }
    __syncthreads();
    if (t < 64) {
      const float s = red[t] + red[128+t] + red[256+t] + red[384+t];
      const float qq = red[64+t] + red[192+t] + red[320+t] + red[448+t];
      partials[(size_t)t*PST + blockIdx.x]      = s;
      partials[(size_t)(64+t)*PST + blockIdx.x] = qq;
    }
  }
}

// ---------------------------------------------------------------------------
__global__ __launch_bounds__(256) void fin_k(const float* __restrict__ partials,
    int nblk, const float* __restrict__ gamma, const float* __restrict__ beta,
    float* __restrict__ ss, float invN)
{
  __shared__ float red[8];
  const int c = blockIdx.x;
  float s = 0.f, q = 0.f;
  for (int i = threadIdx.x; i < nblk; i += 256) {
    s += partials[(size_t)c*PST + i];
    q += partials[(size_t)(64+c)*PST + i];
  }
#pragma unroll
  for (int mk = 1; mk < 64; mk <<= 1) {
    s += __shfl_xor(s, mk);
    q += __shfl_xor(q, mk);
  }
  const int w = threadIdx.x >> 6;
  if ((threadIdx.x & 63) == 0) { red[w*2] = s; red[w*2+1] = q; }
  __syncthreads();
  if (threadIdx.x == 0) {
    const float S = red[0]+red[2]+red[4]+red[6];
    const float Q = red[1]+red[3]+red[5]+red[7];
    const float mean = S*invN;
    const float var  = Q*invN - mean*mean;
    const float scale = gamma[c] * rsqrtf(var + EPSV);
    ss[c] = scale; ss[64+c] = beta[c] - mean*scale;
  }
}

// ---------------------------------------------------------------------------
// MFMA mixer v2: constants in LDS (low VGPR -> high occupancy), V folded as
// a K=16 B-fragment MFMA (vt[tt][j] at lane(r16,q) IS B_V[k=4q+j][c=16tt+r16]).
__global__ __launch_bounds__(256, 6) void mixer_k(
    const float* __restrict__ p, const int* __restrict__ knn,
    const u16* __restrict__ v16, const u16* __restrict__ hw16,
    const uint4* __restrict__ frags,   // wwf[0:128] wp2f[128:640] w1f[640:1024]
    u16* __restrict__ mx16, float* __restrict__ partials, int N)
{
  __shared__ uint4 cst[1024];   // 16 KB constants
  __shared__ float red[512];
  const int t = threadIdx.x, lane = t & 63, w = t >> 6;
  const int r16 = lane & 15, q = lane >> 4, b = r16 >> 3;

  for (int e = t; e < 1024; e += 256) cst[e] = frags[e];
  __syncthreads();

  float ssum = 0.f, sq = 0.f;
  const int nwaves = gridDim.x * 4;

  for (int i = blockIdx.x*4 + w; i < N; i += nwaves) {
    // ---- gathers (vmem pipe, issued early) ----
    const int4 kn4 = *(const int4*)(knn + (size_t)i*16 + 4*q);
    const int kn[4] = {kn4.x, kn4.y, kn4.z, kn4.w};
    const int jj = knn[(size_t)i*16 + r16];
    unsigned vtp[4][2];   // packed V B-frags per tile
#pragma unroll
    for (int tt = 0; tt < 4; ++tt) {
      const unsigned v0 = v16[(size_t)kn[0]*64 + 16*tt + r16];
      const unsigned v1 = v16[(size_t)kn[1]*64 + 16*tt + r16];
      const unsigned v2 = v16[(size_t)kn[2]*64 + 16*tt + r16];
      const unsigned v3 = v16[(size_t)kn[3]*64 + 16*tt + r16];
      vtp[tt][0] = v0 | (v1 << 16);
      vtp[tt][1] = v2 | (v3 << 16);
    }
    unsigned hvu[4];
#pragma unroll
    for (int j = 0; j < 4; ++j) hvu[j] = hw16[(size_t)kn[j]*8 + r16];
    const float2 pj2 = *(const float2*)(p + (size_t)jj*3);
    const float pjz  = p[(size_t)jj*3 + 2];
    const float dx = pj2.x - p[(size_t)i*3];
    const float dy = pj2.y - p[(size_t)i*3+1];
    const float dz = pjz   - p[(size_t)i*3+2];

    // ---- e' fragments (packed f16, w1 from LDS) ----
    const h2_t dx2 = __builtin_bit_cast(h2_t, pkrtz(dx, dx));
    const h2_t dy2 = __builtin_bit_cast(h2_t, pkrtz(dy, dy));
    const h2_t dz2 = __builtin_bit_cast(h2_t, pkrtz(dz, dz));
    f16x8 eA[2];
#pragma unroll
    for (int h = 0; h < 2; ++h) {
      const uint4 wx = cst[640 + h*64 + lane];        // Wp1 row x, half h
      const uint4 wy = cst[640 + (2+h)*64 + lane];    // row y
      const uint4 wz = cst[640 + (4+h)*64 + lane];    // row z
      unsigned eu[4];
      const unsigned* wxp = &wx.x; const unsigned* wyp = &wy.x; const unsigned* wzp = &wz.x;
#pragma unroll
      for (int mm = 0; mm < 4; ++mm) {
        h2_t acc = dz2 * __builtin_bit_cast(h2_t, wzp[mm]);
        acc = dy2 * __builtin_bit_cast(h2_t, wyp[mm]) + acc;
        acc = dx2 * __builtin_bit_cast(h2_t, wxp[mm]) + acc;
        eu[mm] = relu2(__builtin_bit_cast(unsigned, acc));
      }
      eA[h] = mk8(eu[0], eu[1], eu[2], eu[3]);
    }

    // ---- energy[k][g] via MFMA + hw bias ----
    f32x4 en = {0.f, 0.f, 0.f, 0.f};
    en = mfma16(eA[0], __builtin_bit_cast(f16x8, cst[lane]), en);
    en = mfma16(eA[1], __builtin_bit_cast(f16x8, cst[64 + lane]), en);
#pragma unroll
    for (int j = 0; j < 4; ++j) {
      const h2_t hv = __builtin_bit_cast(h2_t, hvu[j]);
      en[j] += (r16 < 8) ? (float)hv[0] : 0.f;
    }

    // ---- softmax over k ----
    float m = fmaxf(fmaxf(en[0], en[1]), fmaxf(en[2], en[3]));
    m = fmaxf(m, __shfl_xor(m, 16));
    m = fmaxf(m, __shfl_xor(m, 32));
    const float e0 = __expf(en[0]-m), e1 = __expf(en[1]-m);
    const float e2 = __expf(en[2]-m), e3 = __expf(en[3]-m);
    float s = e0 + e1 + e2 + e3;
    s += __shfl_xor(s, 16);
    s += __shfl_xor(s, 32);
    const float rs = 1.f / s;
    const f16x4 aw = mk4(pkrtz(e0*rs, e1*rs), pkrtz(e2*rs, e3*rs));

    // ---- per c-tile: E = e'@Wp2; G = w@V + w@E; extract ----
    float outv = 0.f;
#pragma unroll
    for (int tt = 0; tt < 4; ++tt) {
      f32x4 E = {0.f, 0.f, 0.f, 0.f};
      E = mfma16(eA[0], __builtin_bit_cast(f16x8, cst[128 + (tt*2)*64 + lane]), E);
      E = mfma16(eA[1], __builtin_bit_cast(f16x8, cst[128 + (tt*2+1)*64 + lane]), E);
      const f16x4 bE = mk4(pkrtz(E[0], E[1]), pkrtz(E[2], E[3]));
      const f16x4 bV = mk4(vtp[tt][0], vtp[tt][1]);
      f32x4 G = {0.f, 0.f, 0.f, 0.f};
      G = mfma16k16(aw, bV, G);
      G = mfma16k16(aw, bE, G);
      const float sel = b ? G[(2*tt+1) & 3] : G[(2*tt) & 3];
      const float val = __shfl(sel, ((tt >= 2) ? 16 : 0) + r16);
      if (q == tt) outv = val;
    }
    mx16[(size_t)i*64 + lane] = f16b(outv);
    ssum += outv; sq = fmaf(outv, outv, sq);
  }
  __syncthreads();
  red[w*128 + lane] = ssum; red[w*128 + 64 + lane] = sq;
  __syncthreads();
  if (t < 64) {
    const float s = red[t] + red[128+t] + red[256+t] + red[384+t];
    const float qv = red[64+t] + red[192+t] + red[320+t] + red[448+t];
    partials[(size_t)t*PST + blockIdx.x]      = s;
    partials[(size_t)(64+t)*PST + blockIdx.x] = qv;
  }
}

// ---------------------------------------------------------------------------
__global__ __launch_bounds__(256) void final_k(const u16* __restrict__ y16,
    const float* __restrict__ x, const float* __restrict__ ss,
    float* __restrict__ out, int n4)
{
  __shared__ float sl[128];
  if (threadIdx.x < 128) sl[threadIdx.x] = ss[threadIdx.x];
  __syncthreads();
  for (int idx = blockIdx.x*256 + threadIdx.x; idx < n4; idx += gridDim.x*256) {
    const int cb = (idx & 15) << 2;
    const uint2 yu = *(const uint2*)(y16 + (size_t)idx*4);
    const h2_t ylo = __builtin_bit_cast(h2_t, yu.x);
    const h2_t yhi = __builtin_bit_cast(h2_t, yu.y);
    const float4 xx = ((const float4*)x)[idx];
    float4 o;
    o.x = frelu(fmaf((float)ylo[0], sl[cb],   sl[64+cb])   + xx.x);
    o.y = frelu(fmaf((float)ylo[1], sl[cb+1], sl[64+cb+1]) + xx.y);
    o.z = frelu(fmaf((float)yhi[0], sl[cb+2], sl[64+cb+2]) + xx.z);
    o.w = frelu(fmaf((float)yhi[1], sl[cb+3], sl[64+cb+3]) + xx.w);
    ((float4*)out)[idx] = o;
  }
}

// ---------------------------------------------------------------------------
extern "C" void kernel_launch(void* const* d_in, const int* in_sizes, int n_in,
                              void* d_out, int out_size, void* d_ws, size_t ws_size,
                              hipStream_t stream)
{
  (void)n_in; (void)out_size; (void)ws_size;
  const float* p   = (const float*)d_in[0];
  const float* x   = (const float*)d_in[1];
  const int*   knn = (const int*)  d_in[2];
  const float* W1  = (const float*)d_in[3];
  const float* Wv  = (const float*)d_in[4];
  const float* Wp1 = (const float*)d_in[5];
  const float* Wp2 = (const float*)d_in[6];
  const float* Ww  = (const float*)d_in[7];
  const float* W3  = (const float*)d_in[8];
  const float* g1  = (const float*)d_in[9];
  const float* b1  = (const float*)d_in[10];
  const float* g2  = (const float*)d_in[11];
  const float* b2  = (const float*)d_in[12];
  const float* g3  = (const float*)d_in[13];
  const float* b3  = (const float*)d_in[14];
  const int N = in_sizes[0] / 3;
  const float invN = 1.f / (float)N;

  u16* ws16 = (u16*)d_ws;
  u16* y16   = ws16;                       // N*64 f16 (y1, then y3)
  u16* v16   = y16 + (size_t)N*64;         // N*64 f16
  u16* mx16  = v16 + (size_t)N*64;         // N*64 f16
  u16* hw16  = mx16 + (size_t)N*64;        // N*8 f16
  uint4* fr  = (uint4*)(hw16 + (size_t)N*8);  // frag buffers (contiguous)
  uint4* wwf  = fr;                        // 128 uint4
  uint4* wp2f = fr + 128;                  // 512 uint4
  uint4* w1f  = fr + 640;                  // 384 uint4
  float* partials = (float*)(fr + 1024);   // 128*PST f32
  float* ss1      = partials + (size_t)128*PST;
  float* ss2      = ss1 + 128;
  float* ss3      = ss2 + 128;

  gemm_mfma_k<0, false><<<GRID_GEMM + 1, 256, 0, stream>>>(
      x, W1, Ww, nullptr, y16, nullptr, partials, N, Wp2, Wp1, wwf, wp2f, w1f);
  fin_k<<<64, 256, 0, stream>>>(partials, GRID_GEMM, g1, b1, ss1, invN);
  gemm_mfma_k<1, true><<<GRID_GEMM, 256, 0, stream>>>(
      y16, Wv, Ww, ss1, v16, hw16, nullptr, N, nullptr, nullptr, nullptr, nullptr, nullptr);
  mixer_k<<<GRID_MIX, 256, 0, stream>>>(p, knn, v16, hw16, fr, mx16, partials, N);
  fin_k<<<64, 256, 0, stream>>>(partials, GRID_MIX, g2, b2, ss2, invN);
  gemm_mfma_k<2, true><<<GRID_GEMM, 256, 0, stream>>>(
      mx16, W3, nullptr, ss2, y16, nullptr, partials, N, nullptr, nullptr, nullptr, nullptr, nullptr);
  fin_k<<<64, 256, 0, stream>>>(partials, GRID_GEMM, g3, b3, ss3, invN);
  final_k<<<GRID_ELT, 256, 0, stream>>>(y16, x, ss3, (float*)d_out, N*16);
}

// Round 11
// 214.692 us; speedup vs baseline: 1.3133x; 1.3133x over previous
//
#include <hip/hip_runtime.h>
#include <hip/hip_fp16.h>

#define EPSV 1e-5f
#define PST 2048
#define GRID_GEMM 1563
#define GRID_MIX  2048
#define GRID_ELT  2048

typedef _Float16 h2_t  __attribute__((ext_vector_type(2)));  // packed arithmetic
typedef __fp16   fp16x2 __attribute__((ext_vector_type(2))); // builtin interop
typedef _Float16 f16x4 __attribute__((ext_vector_type(4)));  // MFMA K=16 A/B frag
typedef _Float16 f16x8 __attribute__((ext_vector_type(8)));  // MFMA K=32 A/B frag
typedef float    f32x4 __attribute__((ext_vector_type(4)));  // MFMA C/D frag
typedef unsigned short u16;

__device__ __forceinline__ float frelu(float x) { return fmaxf(x, 0.f); }

__device__ __forceinline__ unsigned int pkrtz(float lo, float hi) {
  fp16x2 h = __builtin_amdgcn_cvt_pkrtz(lo, hi);
  return __builtin_bit_cast(unsigned int, h);
}
__device__ __forceinline__ u16 f16b(float x) {
  return (u16)(pkrtz(x, 0.f) & 0xffffu);
}
__device__ __forceinline__ f16x8 mk8(unsigned a, unsigned b, unsigned c, unsigned d) {
  uint4 u; u.x = a; u.y = b; u.z = c; u.w = d;
  return __builtin_bit_cast(f16x8, u);
}
__device__ __forceinline__ f16x4 mk4(unsigned a, unsigned b) {
  uint2 u; u.x = a; u.y = b;
  return __builtin_bit_cast(f16x4, u);
}
__device__ __forceinline__ f32x4 mfma16(f16x8 a, f16x8 b, f32x4 c) {
  return __builtin_amdgcn_mfma_f32_16x16x32_f16(a, b, c, 0, 0, 0);
}
__device__ __forceinline__ f32x4 mfma16k16(f16x4 a, f16x4 b, f32x4 c) {
  return __builtin_amdgcn_mfma_f32_16x16x16f16(a, b, c, 0, 0, 0);
}
// packed f16 relu via sign-bit masking
__device__ __forceinline__ unsigned relu2(unsigned u) {
  const unsigned m = ((u & 0x80008000u) >> 15) * 0xFFFFu;
  return u & ~m;
}

// ---------------------------------------------------------------------------
// MFMA f16 GEMM: out16[N,64](f16) = preop(in) @ W.
// MODE0 additionally: last block packs ww/wp2/wp1 fragment buffers (then exits).
template<int MODE, bool INF16>
__global__ __launch_bounds__(256, 4) void gemm_mfma_k(
    const void* __restrict__ in, const float* __restrict__ W,
    const float* __restrict__ Ww, const float* __restrict__ ss,
    u16* __restrict__ out16, u16* __restrict__ outw16,
    float* __restrict__ partials, int N,
    const float* __restrict__ Wp2, const float* __restrict__ Wp1,
    uint4* __restrict__ wwf, uint4* __restrict__ wp2f, uint4* __restrict__ w1f)
{
  __shared__ float red[512];
  __shared__ u16 xh[4][16*72];
  const int t = threadIdx.x, lane = t & 63, w = t >> 6;
  const int r16 = lane & 15, q = lane >> 4;

  if (MODE == 0 && blockIdx.x == GRID_GEMM) {
    float* wwl = (float*)&xh[0][0];   // 512 floats
    {
      const int a = t >> 2, qq = t & 3;
      float acc[8] = {0,0,0,0,0,0,0,0};
#pragma unroll
      for (int cc = 0; cc < 16; ++cc) {
        const int c = qq*16 + cc;
        const float wv = Wp2[a*64 + c];
#pragma unroll
        for (int g = 0; g < 8; ++g) acc[g] = fmaf(wv, Ww[c*8 + g], acc[g]);
      }
#pragma unroll
      for (int g = 0; g < 8; ++g) {
        acc[g] += __shfl_xor(acc[g], 1);
        acc[g] += __shfl_xor(acc[g], 2);
      }
      if (qq == 0) {
#pragma unroll
        for (int g = 0; g < 8; ++g) wwl[a*8 + g] = acc[g];
      }
    }
    __syncthreads();
    if (t < 128) {
      const int h = t >> 6, l = t & 63, rr = l & 15, qq = l >> 4;
      uint4 u = {0,0,0,0};
      if (rr < 8) {
        u.x = pkrtz(wwl[(32*h+8*qq+0)*8 + rr], wwl[(32*h+8*qq+1)*8 + rr]);
        u.y = pkrtz(wwl[(32*h+8*qq+2)*8 + rr], wwl[(32*h+8*qq+3)*8 + rr]);
        u.z = pkrtz(wwl[(32*h+8*qq+4)*8 + rr], wwl[(32*h+8*qq+5)*8 + rr]);
        u.w = pkrtz(wwl[(32*h+8*qq+6)*8 + rr], wwl[(32*h+8*qq+7)*8 + rr]);
      }
      wwf[t] = u;
    }
    for (int e = t; e < 512; e += 256) {
      const int tt = e >> 7, h = (e >> 6) & 1, l = e & 63;
      const int c = 16*tt + (l & 15), qq = l >> 4;
      const int d0 = 32*h + 8*qq;
      uint4 u;
      u.x = pkrtz(Wp2[(d0+0)*64 + c], Wp2[(d0+1)*64 + c]);
      u.y = pkrtz(Wp2[(d0+2)*64 + c], Wp2[(d0+3)*64 + c]);
      u.z = pkrtz(Wp2[(d0+4)*64 + c], Wp2[(d0+5)*64 + c]);
      u.w = pkrtz(Wp2[(d0+6)*64 + c], Wp2[(d0+7)*64 + c]);
      wp2f[e] = u;
    }
    for (int e = t; e < 384; e += 256) {
      const int r = e >> 7, h = (e >> 6) & 1, l = e & 63, qq = l >> 4;
      const int d0 = 32*h + 8*qq;
      uint4 u;
      u.x = pkrtz(Wp1[r*64 + d0+0], Wp1[r*64 + d0+1]);
      u.y = pkrtz(Wp1[r*64 + d0+2], Wp1[r*64 + d0+3]);
      u.z = pkrtz(Wp1[r*64 + d0+4], Wp1[r*64 + d0+5]);
      u.w = pkrtz(Wp1[r*64 + d0+6], Wp1[r*64 + d0+7]);
      w1f[e] = u;
    }
    return;
  }

  u16* const xw = &xh[w][0];
  f16x8 bw[2][4];
#pragma unroll
  for (int kb = 0; kb < 2; ++kb) {
#pragma unroll
    for (int tt = 0; tt < 4; ++tt) {
      const int kbase = 32*kb + 8*q;
      const int cc = 16*tt + r16;
      unsigned u0 = pkrtz(W[(kbase+0)*64 + cc], W[(kbase+1)*64 + cc]);
      unsigned u1 = pkrtz(W[(kbase+2)*64 + cc], W[(kbase+3)*64 + cc]);
      unsigned u2 = pkrtz(W[(kbase+4)*64 + cc], W[(kbase+5)*64 + cc]);
      unsigned u3 = pkrtz(W[(kbase+6)*64 + cc], W[(kbase+7)*64 + cc]);
      bw[kb][tt] = mk8(u0, u1, u2, u3);
    }
  }
  f16x8 bg[2];
  if (MODE == 1) {
#pragma unroll
    for (int kb = 0; kb < 2; ++kb) {
      const int kbase = 32*kb + 8*q;
      unsigned u[4];
#pragma unroll
      for (int mm = 0; mm < 4; ++mm) {
        float g0 = (r16 < 8) ? Ww[(kbase + 2*mm    )*8 + r16] : 0.f;
        float g1 = (r16 < 8) ? Ww[(kbase + 2*mm + 1)*8 + r16] : 0.f;
        u[mm] = pkrtz(g0, g1);
      }
      bg[kb] = mk8(u[0], u[1], u[2], u[3]);
    }
  }
  float sc4[4], sh4[4];
  if (MODE != 0) {
#pragma unroll
    for (int j = 0; j < 4; ++j) {
      sc4[j] = ss[4*r16 + j];
      sh4[j] = ss[64 + 4*r16 + j];
    }
  }

  float S4[4] = {0,0,0,0}, Q4[4] = {0,0,0,0};
  const int ntiles = (N + 15) >> 4;
  for (int tile = blockIdx.x*4 + w; tile < ntiles; tile += GRID_GEMM*4) {
    const int r0 = tile << 4;
    const bool full = (r0 + 16 <= N);
#pragma unroll
    for (int i = 0; i < 4; ++i) {
      const int row = q + 4*i;
      float4 xv = {0.f, 0.f, 0.f, 0.f};
      const bool rok = full || (r0 + row < N);
      if (rok) {
        if constexpr (INF16) {
          const uint2 u = *(const uint2*)((const u16*)in + (size_t)(r0 + row)*64 + 4*r16);
          const h2_t lo = __builtin_bit_cast(h2_t, u.x);
          const h2_t hi = __builtin_bit_cast(h2_t, u.y);
          xv.x = (float)lo[0]; xv.y = (float)lo[1];
          xv.z = (float)hi[0]; xv.w = (float)hi[1];
        } else {
          xv = *(const float4*)((const float*)in + (size_t)(r0 + row)*64 + 4*r16);
        }
      }
      if (MODE != 0) {
        xv.x = frelu(fmaf(xv.x, sc4[0], sh4[0]));
        xv.y = frelu(fmaf(xv.y, sc4[1], sh4[1]));
        xv.z = frelu(fmaf(xv.z, sc4[2], sh4[2]));
        xv.w = frelu(fmaf(xv.w, sc4[3], sh4[3]));
        if (!rok) { xv.x = 0.f; xv.y = 0.f; xv.z = 0.f; xv.w = 0.f; }
      }
      uint2 u2v; u2v.x = pkrtz(xv.x, xv.y); u2v.y = pkrtz(xv.z, xv.w);
      *(uint2*)(xw + row*72 + 4*r16) = u2v;
    }
    const f16x8 a0 = __builtin_bit_cast(f16x8, *(const uint4*)(xw + r16*72 + 8*q));
    const f16x8 a1 = __builtin_bit_cast(f16x8, *(const uint4*)(xw + r16*72 + 8*q + 32));
    f32x4 acc[4];
#pragma unroll
    for (int tt = 0; tt < 4; ++tt) {
      f32x4 z = {0.f, 0.f, 0.f, 0.f};
      z = mfma16(a0, bw[0][tt], z);
      acc[tt] = mfma16(a1, bw[1][tt], z);
    }
#pragma unroll
    for (int tt = 0; tt < 4; ++tt) {
#pragma unroll
      for (int j = 0; j < 4; ++j) {
        if (full || (r0 + 4*q + j < N))
          out16[(size_t)(r0 + 4*q + j)*64 + 16*tt + r16] = f16b(acc[tt][j]);
      }
      if (MODE != 1) {
        S4[tt] += acc[tt][0] + acc[tt][1] + acc[tt][2] + acc[tt][3];
        Q4[tt] = fmaf(acc[tt][0], acc[tt][0], Q4[tt]);
        Q4[tt] = fmaf(acc[tt][1], acc[tt][1], Q4[tt]);
        Q4[tt] = fmaf(acc[tt][2], acc[tt][2], Q4[tt]);
        Q4[tt] = fmaf(acc[tt][3], acc[tt][3], Q4[tt]);
      }
    }
    if (MODE == 1) {
      f32x4 accw = {0.f, 0.f, 0.f, 0.f};
      accw = mfma16(a0, bg[0], accw);
      accw = mfma16(a1, bg[1], accw);
      if (r16 < 8) {
#pragma unroll
        for (int j = 0; j < 4; ++j) {
          if (full || (r0 + 4*q + j < N))
            outw16[(size_t)(r0 + 4*q + j)*8 + r16] = f16b(accw[j]);
        }
      }
    }
  }
  if (MODE != 1) {
#pragma unroll
    for (int tt = 0; tt < 4; ++tt) {
      S4[tt] += __shfl_xor(S4[tt], 16); S4[tt] += __shfl_xor(S4[tt], 32);
      Q4[tt] += __shfl_xor(Q4[tt], 16); Q4[tt] += __shfl_xor(Q4[tt], 32);
    }
    if (lane < 16) {
#pragma unroll
      for (int tt = 0; tt < 4; ++tt) {
        red[w*128 + tt*16 + lane]      = S4[tt];
        red[w*128 + 64 + tt*16 + lane] = Q4[tt];
      }
    }
    __syncthreads();
    if (t < 64) {
      const float s = red[t] + red[128+t] + red[256+t] + red[384+t];
      const float qq = red[64+t] + red[192+t] + red[320+t] + red[448+t];
      partials[(size_t)t*PST + blockIdx.x]      = s;
      partials[(size_t)(64+t)*PST + blockIdx.x] = qq;
    }
  }
}

// ---------------------------------------------------------------------------
__global__ __launch_bounds__(256) void fin_k(const float* __restrict__ partials,
    int nblk, const float* __restrict__ gamma, const float* __restrict__ beta,
    float* __restrict__ ss, float invN)
{
  __shared__ float red[8];
  const int c = blockIdx.x;
  float s = 0.f, q = 0.f;
  for (int i = threadIdx.x; i < nblk; i += 256) {
    s += partials[(size_t)c*PST + i];
    q += partials[(size_t)(64+c)*PST + i];
  }
#pragma unroll
  for (int mk = 1; mk < 64; mk <<= 1) {
    s += __shfl_xor(s, mk);
    q += __shfl_xor(q, mk);
  }
  const int w = threadIdx.x >> 6;
  if ((threadIdx.x & 63) == 0) { red[w*2] = s; red[w*2+1] = q; }
  __syncthreads();
  if (threadIdx.x == 0) {
    const float S = red[0]+red[2]+red[4]+red[6];
    const float Q = red[1]+red[3]+red[5]+red[7];
    const float mean = S*invN;
    const float var  = Q*invN - mean*mean;
    const float scale = gamma[c] * rsqrtf(var + EPSV);
    ss[c] = scale; ss[64+c] = beta[c] - mean*scale;
  }
}

// ---------------------------------------------------------------------------
// MFMA mixer v2: constants in LDS, V folded as K=16 B-frag MFMA.
// launch_bounds(256,5): ~102 unified regs/wave — fits without spilling
// (256,6 => 85 regs: SPILLED, R10: WRITE_SIZE 21->99MB, FETCH 143->623MB).
__global__ __launch_bounds__(256, 5) void mixer_k(
    const float* __restrict__ p, const int* __restrict__ knn,
    const u16* __restrict__ v16, const u16* __restrict__ hw16,
    const uint4* __restrict__ frags,   // wwf[0:128] wp2f[128:640] w1f[640:1024]
    u16* __restrict__ mx16, float* __restrict__ partials, int N)
{
  __shared__ uint4 cst[1024];   // 16 KB constants
  __shared__ float red[512];
  const int t = threadIdx.x, lane = t & 63, w = t >> 6;
  const int r16 = lane & 15, q = lane >> 4, b = r16 >> 3;

  for (int e = t; e < 1024; e += 256) cst[e] = frags[e];
  __syncthreads();

  float ssum = 0.f, sq = 0.f;
  const int nwaves = gridDim.x * 4;

  for (int i = blockIdx.x*4 + w; i < N; i += nwaves) {
    // ---- gathers (vmem pipe, issued early) ----
    const int4 kn4 = *(const int4*)(knn + (size_t)i*16 + 4*q);
    const int kn[4] = {kn4.x, kn4.y, kn4.z, kn4.w};
    const int jj = knn[(size_t)i*16 + r16];
    unsigned vtp[4][2];   // packed V B-frags per tile
#pragma unroll
    for (int tt = 0; tt < 4; ++tt) {
      const unsigned v0 = v16[(size_t)kn[0]*64 + 16*tt + r16];
      const unsigned v1 = v16[(size_t)kn[1]*64 + 16*tt + r16];
      const unsigned v2 = v16[(size_t)kn[2]*64 + 16*tt + r16];
      const unsigned v3 = v16[(size_t)kn[3]*64 + 16*tt + r16];
      vtp[tt][0] = v0 | (v1 << 16);
      vtp[tt][1] = v2 | (v3 << 16);
    }
    unsigned hvu[4];
#pragma unroll
    for (int j = 0; j < 4; ++j) hvu[j] = hw16[(size_t)kn[j]*8 + r16];
    const float2 pj2 = *(const float2*)(p + (size_t)jj*3);
    const float pjz  = p[(size_t)jj*3 + 2];
    const float dx = pj2.x - p[(size_t)i*3];
    const float dy = pj2.y - p[(size_t)i*3+1];
    const float dz = pjz   - p[(size_t)i*3+2];

    // ---- e' fragments (packed f16, w1 from LDS) ----
    const h2_t dx2 = __builtin_bit_cast(h2_t, pkrtz(dx, dx));
    const h2_t dy2 = __builtin_bit_cast(h2_t, pkrtz(dy, dy));
    const h2_t dz2 = __builtin_bit_cast(h2_t, pkrtz(dz, dz));
    f16x8 eA[2];
#pragma unroll
    for (int h = 0; h < 2; ++h) {
      const uint4 wx = cst[640 + h*64 + lane];        // Wp1 row x, half h
      const uint4 wy = cst[640 + (2+h)*64 + lane];    // row y
      const uint4 wz = cst[640 + (4+h)*64 + lane];    // row z
      unsigned eu[4];
      const unsigned* wxp = &wx.x; const unsigned* wyp = &wy.x; const unsigned* wzp = &wz.x;
#pragma unroll
      for (int mm = 0; mm < 4; ++mm) {
        h2_t acc = dz2 * __builtin_bit_cast(h2_t, wzp[mm]);
        acc = dy2 * __builtin_bit_cast(h2_t, wyp[mm]) + acc;
        acc = dx2 * __builtin_bit_cast(h2_t, wxp[mm]) + acc;
        eu[mm] = relu2(__builtin_bit_cast(unsigned, acc));
      }
      eA[h] = mk8(eu[0], eu[1], eu[2], eu[3]);
    }

    // ---- energy[k][g] via MFMA + hw bias ----
    f32x4 en = {0.f, 0.f, 0.f, 0.f};
    en = mfma16(eA[0], __builtin_bit_cast(f16x8, cst[lane]), en);
    en = mfma16(eA[1], __builtin_bit_cast(f16x8, cst[64 + lane]), en);
#pragma unroll
    for (int j = 0; j < 4; ++j) {
      const h2_t hv = __builtin_bit_cast(h2_t, hvu[j]);
      en[j] += (r16 < 8) ? (float)hv[0] : 0.f;
    }

    // ---- softmax over k ----
    float m = fmaxf(fmaxf(en[0], en[1]), fmaxf(en[2], en[3]));
    m = fmaxf(m, __shfl_xor(m, 16));
    m = fmaxf(m, __shfl_xor(m, 32));
    const float e0 = __expf(en[0]-m), e1 = __expf(en[1]-m);
    const float e2 = __expf(en[2]-m), e3 = __expf(en[3]-m);
    float s = e0 + e1 + e2 + e3;
    s += __shfl_xor(s, 16);
    s += __shfl_xor(s, 32);
    const float rs = 1.f / s;
    const f16x4 aw = mk4(pkrtz(e0*rs, e1*rs), pkrtz(e2*rs, e3*rs));

    // ---- per c-tile: E = e'@Wp2; G = w@V + w@E; extract ----
    float outv = 0.f;
#pragma unroll
    for (int tt = 0; tt < 4; ++tt) {
      f32x4 E = {0.f, 0.f, 0.f, 0.f};
      E = mfma16(eA[0], __builtin_bit_cast(f16x8, cst[128 + (tt*2)*64 + lane]), E);
      E = mfma16(eA[1], __builtin_bit_cast(f16x8, cst[128 + (tt*2+1)*64 + lane]), E);
      const f16x4 bE = mk4(pkrtz(E[0], E[1]), pkrtz(E[2], E[3]));
      const f16x4 bV = mk4(vtp[tt][0], vtp[tt][1]);
      f32x4 G = {0.f, 0.f, 0.f, 0.f};
      G = mfma16k16(aw, bV, G);
      G = mfma16k16(aw, bE, G);
      const float sel = b ? G[(2*tt+1) & 3] : G[(2*tt) & 3];
      const float val = __shfl(sel, ((tt >= 2) ? 16 : 0) + r16);
      if (q == tt) outv = val;
    }
    mx16[(size_t)i*64 + lane] = f16b(outv);
    ssum += outv; sq = fmaf(outv, outv, sq);
  }
  __syncthreads();
  red[w*128 + lane] = ssum; red[w*128 + 64 + lane] = sq;
  __syncthreads();
  if (t < 64) {
    const float s = red[t] + red[128+t] + red[256+t] + red[384+t];
    const float qv = red[64+t] + red[192+t] + red[320+t] + red[448+t];
    partials[(size_t)t*PST + blockIdx.x]      = s;
    partials[(size_t)(64+t)*PST + blockIdx.x] = qv;
  }
}

// ---------------------------------------------------------------------------
__global__ __launch_bounds__(256) void final_k(const u16* __restrict__ y16,
    const float* __restrict__ x, const float* __restrict__ ss,
    float* __restrict__ out, int n4)
{
  __shared__ float sl[128];
  if (threadIdx.x < 128) sl[threadIdx.x] = ss[threadIdx.x];
  __syncthreads();
  for (int idx = blockIdx.x*256 + threadIdx.x; idx < n4; idx += gridDim.x*256) {
    const int cb = (idx & 15) << 2;
    const uint2 yu = *(const uint2*)(y16 + (size_t)idx*4);
    const h2_t ylo = __builtin_bit_cast(h2_t, yu.x);
    const h2_t yhi = __builtin_bit_cast(h2_t, yu.y);
    const float4 xx = ((const float4*)x)[idx];
    float4 o;
    o.x = frelu(fmaf((float)ylo[0], sl[cb],   sl[64+cb])   + xx.x);
    o.y = frelu(fmaf((float)ylo[1], sl[cb+1], sl[64+cb+1]) + xx.y);
    o.z = frelu(fmaf((float)yhi[0], sl[cb+2], sl[64+cb+2]) + xx.z);
    o.w = frelu(fmaf((float)yhi[1], sl[cb+3], sl[64+cb+3]) + xx.w);
    ((float4*)out)[idx] = o;
  }
}

// ---------------------------------------------------------------------------
extern "C" void kernel_launch(void* const* d_in, const int* in_sizes, int n_in,
                              void* d_out, int out_size, void* d_ws, size_t ws_size,
                              hipStream_t stream)
{
  (void)n_in; (void)out_size; (void)ws_size;
  const float* p   = (const float*)d_in[0];
  const float* x   = (const float*)d_in[1];
  const int*   knn = (const int*)  d_in[2];
  const float* W1  = (const float*)d_in[3];
  const float* Wv  = (const float*)d_in[4];
  const float* Wp1 = (const float*)d_in[5];
  const float* Wp2 = (const float*)d_in[6];
  const float* Ww  = (const float*)d_in[7];
  const float* W3  = (const float*)d_in[8];
  const float* g1  = (const float*)d_in[9];
  const float* b1  = (const float*)d_in[10];
  const float* g2  = (const float*)d_in[11];
  const float* b2  = (const float*)d_in[12];
  const float* g3  = (const float*)d_in[13];
  const float* b3  = (const float*)d_in[14];
  const int N = in_sizes[0] / 3;
  const float invN = 1.f / (float)N;

  u16* ws16 = (u16*)d_ws;
  u16* y16   = ws16;                       // N*64 f16 (y1, then y3)
  u16* v16   = y16 + (size_t)N*64;         // N*64 f16
  u16* mx16  = v16 + (size_t)N*64;         // N*64 f16
  u16* hw16  = mx16 + (size_t)N*64;        // N*8 f16
  uint4* fr  = (uint4*)(hw16 + (size_t)N*8);  // frag buffers (contiguous)
  uint4* wwf  = fr;                        // 128 uint4
  uint4* wp2f = fr + 128;                  // 512 uint4
  uint4* w1f  = fr + 640;                  // 384 uint4
  float* partials = (float*)(fr + 1024);   // 128*PST f32
  float* ss1      = partials + (size_t)128*PST;
  float* ss2      = ss1 + 128;
  float* ss3      = ss2 + 128;

  gemm_mfma_k<0, false><<<GRID_GEMM + 1, 256, 0, stream>>>(
      x, W1, Ww, nullptr, y16, nullptr, partials, N, Wp2, Wp1, wwf, wp2f, w1f);
  fin_k<<<64, 256, 0, stream>>>(partials, GRID_GEMM, g1, b1, ss1, invN);
  gemm_mfma_k<1, true><<<GRID_GEMM, 256, 0, stream>>>(
      y16, Wv, Ww, ss1, v16, hw16, nullptr, N, nullptr, nullptr, nullptr, nullptr, nullptr);
  mixer_k<<<GRID_MIX, 256, 0, stream>>>(p, knn, v16, hw16, fr, mx16, partials, N);
  fin_k<<<64, 256, 0, stream>>>(partials, GRID_MIX, g2, b2, ss2, invN);
  gemm_mfma_k<2, true><<<GRID_GEMM, 256, 0, stream>>>(
      mx16, W3, nullptr, ss2, y16, nullptr, partials, N, nullptr, nullptr, nullptr, nullptr, nullptr);
  fin_k<<<64, 256, 0, stream>>>(partials, GRID_GEMM, g3, b3, ss3, invN);
  final_k<<<GRID_ELT, 256, 0, stream>>>(y16, x, ss3, (float*)d_out, N*16);
}

// Round 12
// 134.826 us; speedup vs baseline: 2.0913x; 1.5924x over previous
//
#include <hip/hip_runtime.h>
#include <hip/hip_fp16.h>

#define EPSV 1e-5f
#define PST 2048
#define GRID_GEMM 1563
#define GRID_MIX  2048
#define GRID_ELT  2048

typedef _Float16 h2_t  __attribute__((ext_vector_type(2)));  // packed arithmetic
typedef __fp16   fp16x2 __attribute__((ext_vector_type(2))); // builtin interop
typedef _Float16 f16x4 __attribute__((ext_vector_type(4)));  // MFMA K=16 A/B frag
typedef _Float16 f16x8 __attribute__((ext_vector_type(8)));  // MFMA K=32 A/B frag
typedef float    f32x4 __attribute__((ext_vector_type(4)));  // MFMA C/D frag
typedef unsigned short u16;

__device__ __forceinline__ float frelu(float x) { return fmaxf(x, 0.f); }

__device__ __forceinline__ unsigned int pkrtz(float lo, float hi) {
  fp16x2 h = __builtin_amdgcn_cvt_pkrtz(lo, hi);
  return __builtin_bit_cast(unsigned int, h);
}
__device__ __forceinline__ u16 f16b(float x) {
  return (u16)(pkrtz(x, 0.f) & 0xffffu);
}
__device__ __forceinline__ f16x8 mk8(unsigned a, unsigned b, unsigned c, unsigned d) {
  uint4 u; u.x = a; u.y = b; u.z = c; u.w = d;
  return __builtin_bit_cast(f16x8, u);
}
__device__ __forceinline__ f16x4 mk4(unsigned a, unsigned b) {
  uint2 u; u.x = a; u.y = b;
  return __builtin_bit_cast(f16x4, u);
}
__device__ __forceinline__ f32x4 mfma16(f16x8 a, f16x8 b, f32x4 c) {
  return __builtin_amdgcn_mfma_f32_16x16x32_f16(a, b, c, 0, 0, 0);
}
__device__ __forceinline__ f32x4 mfma16k16(f16x4 a, f16x4 b, f32x4 c) {
  return __builtin_amdgcn_mfma_f32_16x16x16f16(a, b, c, 0, 0, 0);
}
// packed f16 relu via sign-bit masking
__device__ __forceinline__ unsigned relu2(unsigned u) {
  const unsigned m = ((u & 0x80008000u) >> 15) * 0xFFFFu;
  return u & ~m;
}

// ---------------------------------------------------------------------------
// MFMA f16 GEMM: out16[N,64](f16) = preop(in) @ W.
// MODE0 additionally: last block packs ww/wp2/wp1 fragment buffers (then exits).
template<int MODE, bool INF16>
__global__ __launch_bounds__(256, 4) void gemm_mfma_k(
    const void* __restrict__ in, const float* __restrict__ W,
    const float* __restrict__ Ww, const float* __restrict__ ss,
    u16* __restrict__ out16, u16* __restrict__ outw16,
    float* __restrict__ partials, int N,
    const float* __restrict__ Wp2, const float* __restrict__ Wp1,
    uint4* __restrict__ wwf, uint4* __restrict__ wp2f, uint4* __restrict__ w1f)
{
  __shared__ float red[512];
  __shared__ u16 xh[4][16*72];
  const int t = threadIdx.x, lane = t & 63, w = t >> 6;
  const int r16 = lane & 15, q = lane >> 4;

  if (MODE == 0 && blockIdx.x == GRID_GEMM) {
    float* wwl = (float*)&xh[0][0];   // 512 floats
    {
      const int a = t >> 2, qq = t & 3;
      float acc[8] = {0,0,0,0,0,0,0,0};
#pragma unroll
      for (int cc = 0; cc < 16; ++cc) {
        const int c = qq*16 + cc;
        const float wv = Wp2[a*64 + c];
#pragma unroll
        for (int g = 0; g < 8; ++g) acc[g] = fmaf(wv, Ww[c*8 + g], acc[g]);
      }
#pragma unroll
      for (int g = 0; g < 8; ++g) {
        acc[g] += __shfl_xor(acc[g], 1);
        acc[g] += __shfl_xor(acc[g], 2);
      }
      if (qq == 0) {
#pragma unroll
        for (int g = 0; g < 8; ++g) wwl[a*8 + g] = acc[g];
      }
    }
    __syncthreads();
    if (t < 128) {
      const int h = t >> 6, l = t & 63, rr = l & 15, qq = l >> 4;
      uint4 u = {0,0,0,0};
      if (rr < 8) {
        u.x = pkrtz(wwl[(32*h+8*qq+0)*8 + rr], wwl[(32*h+8*qq+1)*8 + rr]);
        u.y = pkrtz(wwl[(32*h+8*qq+2)*8 + rr], wwl[(32*h+8*qq+3)*8 + rr]);
        u.z = pkrtz(wwl[(32*h+8*qq+4)*8 + rr], wwl[(32*h+8*qq+5)*8 + rr]);
        u.w = pkrtz(wwl[(32*h+8*qq+6)*8 + rr], wwl[(32*h+8*qq+7)*8 + rr]);
      }
      wwf[t] = u;
    }
    for (int e = t; e < 512; e += 256) {
      const int tt = e >> 7, h = (e >> 6) & 1, l = e & 63;
      const int c = 16*tt + (l & 15), qq = l >> 4;
      const int d0 = 32*h + 8*qq;
      uint4 u;
      u.x = pkrtz(Wp2[(d0+0)*64 + c], Wp2[(d0+1)*64 + c]);
      u.y = pkrtz(Wp2[(d0+2)*64 + c], Wp2[(d0+3)*64 + c]);
      u.z = pkrtz(Wp2[(d0+4)*64 + c], Wp2[(d0+5)*64 + c]);
      u.w = pkrtz(Wp2[(d0+6)*64 + c], Wp2[(d0+7)*64 + c]);
      wp2f[e] = u;
    }
    for (int e = t; e < 384; e += 256) {
      const int r = e >> 7, h = (e >> 6) & 1, l = e & 63, qq = l >> 4;
      const int d0 = 32*h + 8*qq;
      uint4 u;
      u.x = pkrtz(Wp1[r*64 + d0+0], Wp1[r*64 + d0+1]);
      u.y = pkrtz(Wp1[r*64 + d0+2], Wp1[r*64 + d0+3]);
      u.z = pkrtz(Wp1[r*64 + d0+4], Wp1[r*64 + d0+5]);
      u.w = pkrtz(Wp1[r*64 + d0+6], Wp1[r*64 + d0+7]);
      w1f[e] = u;
    }
    return;
  }

  u16* const xw = &xh[w][0];
  f16x8 bw[2][4];
#pragma unroll
  for (int kb = 0; kb < 2; ++kb) {
#pragma unroll
    for (int tt = 0; tt < 4; ++tt) {
      const int kbase = 32*kb + 8*q;
      const int cc = 16*tt + r16;
      unsigned u0 = pkrtz(W[(kbase+0)*64 + cc], W[(kbase+1)*64 + cc]);
      unsigned u1 = pkrtz(W[(kbase+2)*64 + cc], W[(kbase+3)*64 + cc]);
      unsigned u2 = pkrtz(W[(kbase+4)*64 + cc], W[(kbase+5)*64 + cc]);
      unsigned u3 = pkrtz(W[(kbase+6)*64 + cc], W[(kbase+7)*64 + cc]);
      bw[kb][tt] = mk8(u0, u1, u2, u3);
    }
  }
  f16x8 bg[2];
  if (MODE == 1) {
#pragma unroll
    for (int kb = 0; kb < 2; ++kb) {
      const int kbase = 32*kb + 8*q;
      unsigned u[4];
#pragma unroll
      for (int mm = 0; mm < 4; ++mm) {
        float g0 = (r16 < 8) ? Ww[(kbase + 2*mm    )*8 + r16] : 0.f;
        float g1 = (r16 < 8) ? Ww[(kbase + 2*mm + 1)*8 + r16] : 0.f;
        u[mm] = pkrtz(g0, g1);
      }
      bg[kb] = mk8(u[0], u[1], u[2], u[3]);
    }
  }
  float sc4[4], sh4[4];
  if (MODE != 0) {
#pragma unroll
    for (int j = 0; j < 4; ++j) {
      sc4[j] = ss[4*r16 + j];
      sh4[j] = ss[64 + 4*r16 + j];
    }
  }

  float S4[4] = {0,0,0,0}, Q4[4] = {0,0,0,0};
  const int ntiles = (N + 15) >> 4;
  for (int tile = blockIdx.x*4 + w; tile < ntiles; tile += GRID_GEMM*4) {
    const int r0 = tile << 4;
    const bool full = (r0 + 16 <= N);
#pragma unroll
    for (int i = 0; i < 4; ++i) {
      const int row = q + 4*i;
      float4 xv = {0.f, 0.f, 0.f, 0.f};
      const bool rok = full || (r0 + row < N);
      if (rok) {
        if constexpr (INF16) {
          const uint2 u = *(const uint2*)((const u16*)in + (size_t)(r0 + row)*64 + 4*r16);
          const h2_t lo = __builtin_bit_cast(h2_t, u.x);
          const h2_t hi = __builtin_bit_cast(h2_t, u.y);
          xv.x = (float)lo[0]; xv.y = (float)lo[1];
          xv.z = (float)hi[0]; xv.w = (float)hi[1];
        } else {
          xv = *(const float4*)((const float*)in + (size_t)(r0 + row)*64 + 4*r16);
        }
      }
      if (MODE != 0) {
        xv.x = frelu(fmaf(xv.x, sc4[0], sh4[0]));
        xv.y = frelu(fmaf(xv.y, sc4[1], sh4[1]));
        xv.z = frelu(fmaf(xv.z, sc4[2], sh4[2]));
        xv.w = frelu(fmaf(xv.w, sc4[3], sh4[3]));
        if (!rok) { xv.x = 0.f; xv.y = 0.f; xv.z = 0.f; xv.w = 0.f; }
      }
      uint2 u2v; u2v.x = pkrtz(xv.x, xv.y); u2v.y = pkrtz(xv.z, xv.w);
      *(uint2*)(xw + row*72 + 4*r16) = u2v;
    }
    const f16x8 a0 = __builtin_bit_cast(f16x8, *(const uint4*)(xw + r16*72 + 8*q));
    const f16x8 a1 = __builtin_bit_cast(f16x8, *(const uint4*)(xw + r16*72 + 8*q + 32));
    f32x4 acc[4];
#pragma unroll
    for (int tt = 0; tt < 4; ++tt) {
      f32x4 z = {0.f, 0.f, 0.f, 0.f};
      z = mfma16(a0, bw[0][tt], z);
      acc[tt] = mfma16(a1, bw[1][tt], z);
    }
#pragma unroll
    for (int tt = 0; tt < 4; ++tt) {
#pragma unroll
      for (int j = 0; j < 4; ++j) {
        if (full || (r0 + 4*q + j < N))
          out16[(size_t)(r0 + 4*q + j)*64 + 16*tt + r16] = f16b(acc[tt][j]);
      }
      if (MODE != 1) {
        S4[tt] += acc[tt][0] + acc[tt][1] + acc[tt][2] + acc[tt][3];
        Q4[tt] = fmaf(acc[tt][0], acc[tt][0], Q4[tt]);
        Q4[tt] = fmaf(acc[tt][1], acc[tt][1], Q4[tt]);
        Q4[tt] = fmaf(acc[tt][2], acc[tt][2], Q4[tt]);
        Q4[tt] = fmaf(acc[tt][3], acc[tt][3], Q4[tt]);
      }
    }
    if (MODE == 1) {
      f32x4 accw = {0.f, 0.f, 0.f, 0.f};
      accw = mfma16(a0, bg[0], accw);
      accw = mfma16(a1, bg[1], accw);
      if (r16 < 8) {
#pragma unroll
        for (int j = 0; j < 4; ++j) {
          if (full || (r0 + 4*q + j < N))
            outw16[(size_t)(r0 + 4*q + j)*8 + r16] = f16b(accw[j]);
        }
      }
    }
  }
  if (MODE != 1) {
#pragma unroll
    for (int tt = 0; tt < 4; ++tt) {
      S4[tt] += __shfl_xor(S4[tt], 16); S4[tt] += __shfl_xor(S4[tt], 32);
      Q4[tt] += __shfl_xor(Q4[tt], 16); Q4[tt] += __shfl_xor(Q4[tt], 32);
    }
    if (lane < 16) {
#pragma unroll
      for (int tt = 0; tt < 4; ++tt) {
        red[w*128 + tt*16 + lane]      = S4[tt];
        red[w*128 + 64 + tt*16 + lane] = Q4[tt];
      }
    }
    __syncthreads();
    if (t < 64) {
      const float s = red[t] + red[128+t] + red[256+t] + red[384+t];
      const float qq = red[64+t] + red[192+t] + red[320+t] + red[448+t];
      partials[(size_t)t*PST + blockIdx.x]      = s;
      partials[(size_t)(64+t)*PST + blockIdx.x] = qq;
    }
  }
}

// ---------------------------------------------------------------------------
__global__ __launch_bounds__(256) void fin_k(const float* __restrict__ partials,
    int nblk, const float* __restrict__ gamma, const float* __restrict__ beta,
    float* __restrict__ ss, float invN)
{
  __shared__ float red[8];
  const int c = blockIdx.x;
  float s = 0.f, q = 0.f;
  for (int i = threadIdx.x; i < nblk; i += 256) {
    s += partials[(size_t)c*PST + i];
    q += partials[(size_t)(64+c)*PST + i];
  }
#pragma unroll
  for (int mk = 1; mk < 64; mk <<= 1) {
    s += __shfl_xor(s, mk);
    q += __shfl_xor(q, mk);
  }
  const int w = threadIdx.x >> 6;
  if ((threadIdx.x & 63) == 0) { red[w*2] = s; red[w*2+1] = q; }
  __syncthreads();
  if (threadIdx.x == 0) {
    const float S = red[0]+red[2]+red[4]+red[6];
    const float Q = red[1]+red[3]+red[5]+red[7];
    const float mean = S*invN;
    const float var  = Q*invN - mean*mean;
    const float scale = gamma[c] * rsqrtf(var + EPSV);
    ss[c] = scale; ss[64+c] = beta[c] - mean*scale;
  }
}

// ---------------------------------------------------------------------------
// MFMA mixer v2: constants in LDS, V folded as K=16 B-frag MFMA.
// launch_bounds(256,4): same 128-reg budget that held spill-free in R8
// with MORE live values — strictly safe; freed regs let HW grant >4 waves.
// ((256,5)=102 regs and (256,6)=85 regs both SPILLED: R10/R11 FETCH blowup.)
__global__ __launch_bounds__(256, 4) void mixer_k(
    const float* __restrict__ p, const int* __restrict__ knn,
    const u16* __restrict__ v16, const u16* __restrict__ hw16,
    const uint4* __restrict__ frags,   // wwf[0:128] wp2f[128:640] w1f[640:1024]
    u16* __restrict__ mx16, float* __restrict__ partials, int N)
{
  __shared__ uint4 cst[1024];   // 16 KB constants
  __shared__ float red[512];
  const int t = threadIdx.x, lane = t & 63, w = t >> 6;
  const int r16 = lane & 15, q = lane >> 4, b = r16 >> 3;

  for (int e = t; e < 1024; e += 256) cst[e] = frags[e];
  __syncthreads();

  float ssum = 0.f, sq = 0.f;
  const int nwaves = gridDim.x * 4;

  for (int i = blockIdx.x*4 + w; i < N; i += nwaves) {
    // ---- gathers (vmem pipe, issued early) ----
    const int4 kn4 = *(const int4*)(knn + (size_t)i*16 + 4*q);
    const int kn[4] = {kn4.x, kn4.y, kn4.z, kn4.w};
    const int jj = knn[(size_t)i*16 + r16];
    unsigned vtp[4][2];   // packed V B-frags per tile
#pragma unroll
    for (int tt = 0; tt < 4; ++tt) {
      const unsigned v0 = v16[(size_t)kn[0]*64 + 16*tt + r16];
      const unsigned v1 = v16[(size_t)kn[1]*64 + 16*tt + r16];
      const unsigned v2 = v16[(size_t)kn[2]*64 + 16*tt + r16];
      const unsigned v3 = v16[(size_t)kn[3]*64 + 16*tt + r16];
      vtp[tt][0] = v0 | (v1 << 16);
      vtp[tt][1] = v2 | (v3 << 16);
    }
    unsigned hvu[4];
#pragma unroll
    for (int j = 0; j < 4; ++j) hvu[j] = hw16[(size_t)kn[j]*8 + r16];
    const float2 pj2 = *(const float2*)(p + (size_t)jj*3);
    const float pjz  = p[(size_t)jj*3 + 2];
    const float dx = pj2.x - p[(size_t)i*3];
    const float dy = pj2.y - p[(size_t)i*3+1];
    const float dz = pjz   - p[(size_t)i*3+2];

    // ---- e' fragments (packed f16, w1 from LDS) ----
    const h2_t dx2 = __builtin_bit_cast(h2_t, pkrtz(dx, dx));
    const h2_t dy2 = __builtin_bit_cast(h2_t, pkrtz(dy, dy));
    const h2_t dz2 = __builtin_bit_cast(h2_t, pkrtz(dz, dz));
    f16x8 eA[2];
#pragma unroll
    for (int h = 0; h < 2; ++h) {
      const uint4 wx = cst[640 + h*64 + lane];        // Wp1 row x, half h
      const uint4 wy = cst[640 + (2+h)*64 + lane];    // row y
      const uint4 wz = cst[640 + (4+h)*64 + lane];    // row z
      unsigned eu[4];
      const unsigned* wxp = &wx.x; const unsigned* wyp = &wy.x; const unsigned* wzp = &wz.x;
#pragma unroll
      for (int mm = 0; mm < 4; ++mm) {
        h2_t acc = dz2 * __builtin_bit_cast(h2_t, wzp[mm]);
        acc = dy2 * __builtin_bit_cast(h2_t, wyp[mm]) + acc;
        acc = dx2 * __builtin_bit_cast(h2_t, wxp[mm]) + acc;
        eu[mm] = relu2(__builtin_bit_cast(unsigned, acc));
      }
      eA[h] = mk8(eu[0], eu[1], eu[2], eu[3]);
    }

    // ---- energy[k][g] via MFMA + hw bias ----
    f32x4 en = {0.f, 0.f, 0.f, 0.f};
    en = mfma16(eA[0], __builtin_bit_cast(f16x8, cst[lane]), en);
    en = mfma16(eA[1], __builtin_bit_cast(f16x8, cst[64 + lane]), en);
#pragma unroll
    for (int j = 0; j < 4; ++j) {
      const h2_t hv = __builtin_bit_cast(h2_t, hvu[j]);
      en[j] += (r16 < 8) ? (float)hv[0] : 0.f;
    }

    // ---- softmax over k ----
    float m = fmaxf(fmaxf(en[0], en[1]), fmaxf(en[2], en[3]));
    m = fmaxf(m, __shfl_xor(m, 16));
    m = fmaxf(m, __shfl_xor(m, 32));
    const float e0 = __expf(en[0]-m), e1 = __expf(en[1]-m);
    const float e2 = __expf(en[2]-m), e3 = __expf(en[3]-m);
    float s = e0 + e1 + e2 + e3;
    s += __shfl_xor(s, 16);
    s += __shfl_xor(s, 32);
    const float rs = 1.f / s;
    const f16x4 aw = mk4(pkrtz(e0*rs, e1*rs), pkrtz(e2*rs, e3*rs));

    // ---- per c-tile: E = e'@Wp2; G = w@V + w@E; extract ----
    float outv = 0.f;
#pragma unroll
    for (int tt = 0; tt < 4; ++tt) {
      f32x4 E = {0.f, 0.f, 0.f, 0.f};
      E = mfma16(eA[0], __builtin_bit_cast(f16x8, cst[128 + (tt*2)*64 + lane]), E);
      E = mfma16(eA[1], __builtin_bit_cast(f16x8, cst[128 + (tt*2+1)*64 + lane]), E);
      const f16x4 bE = mk4(pkrtz(E[0], E[1]), pkrtz(E[2], E[3]));
      const f16x4 bV = mk4(vtp[tt][0], vtp[tt][1]);
      f32x4 G = {0.f, 0.f, 0.f, 0.f};
      G = mfma16k16(aw, bV, G);
      G = mfma16k16(aw, bE, G);
      const float sel = b ? G[(2*tt+1) & 3] : G[(2*tt) & 3];
      const float val = __shfl(sel, ((tt >= 2) ? 16 : 0) + r16);
      if (q == tt) outv = val;
    }
    mx16[(size_t)i*64 + lane] = f16b(outv);
    ssum += outv; sq = fmaf(outv, outv, sq);
  }
  __syncthreads();
  red[w*128 + lane] = ssum; red[w*128 + 64 + lane] = sq;
  __syncthreads();
  if (t < 64) {
    const float s = red[t] + red[128+t] + red[256+t] + red[384+t];
    const float qv = red[64+t] + red[192+t] + red[320+t] + red[448+t];
    partials[(size_t)t*PST + blockIdx.x]      = s;
    partials[(size_t)(64+t)*PST + blockIdx.x] = qv;
  }
}

// ---------------------------------------------------------------------------
__global__ __launch_bounds__(256) void final_k(const u16* __restrict__ y16,
    const float* __restrict__ x, const float* __restrict__ ss,
    float* __restrict__ out, int n4)
{
  __shared__ float sl[128];
  if (threadIdx.x < 128) sl[threadIdx.x] = ss[threadIdx.x];
  __syncthreads();
  for (int idx = blockIdx.x*256 + threadIdx.x; idx < n4; idx += gridDim.x*256) {
    const int cb = (idx & 15) << 2;
    const uint2 yu = *(const uint2*)(y16 + (size_t)idx*4);
    const h2_t ylo = __builtin_bit_cast(h2_t, yu.x);
    const h2_t yhi = __builtin_bit_cast(h2_t, yu.y);
    const float4 xx = ((const float4*)x)[idx];
    float4 o;
    o.x = frelu(fmaf((float)ylo[0], sl[cb],   sl[64+cb])   + xx.x);
    o.y = frelu(fmaf((float)ylo[1], sl[cb+1], sl[64+cb+1]) + xx.y);
    o.z = frelu(fmaf((float)yhi[0], sl[cb+2], sl[64+cb+2]) + xx.z);
    o.w = frelu(fmaf((float)yhi[1], sl[cb+3], sl[64+cb+3]) + xx.w);
    ((float4*)out)[idx] = o;
  }
}

// ---------------------------------------------------------------------------
extern "C" void kernel_launch(void* const* d_in, const int* in_sizes, int n_in,
                              void* d_out, int out_size, void* d_ws, size_t ws_size,
                              hipStream_t stream)
{
  (void)n_in; (void)out_size; (void)ws_size;
  const float* p   = (const float*)d_in[0];
  const float* x   = (const float*)d_in[1];
  const int*   knn = (const int*)  d_in[2];
  const float* W1  = (const float*)d_in[3];
  const float* Wv  = (const float*)d_in[4];
  const float* Wp1 = (const float*)d_in[5];
  const float* Wp2 = (const float*)d_in[6];
  const float* Ww  = (const float*)d_in[7];
  const float* W3  = (const float*)d_in[8];
  const float* g1  = (const float*)d_in[9];
  const float* b1  = (const float*)d_in[10];
  const float* g2  = (const float*)d_in[11];
  const float* b2  = (const float*)d_in[12];
  const float* g3  = (const float*)d_in[13];
  const float* b3  = (const float*)d_in[14];
  const int N = in_sizes[0] / 3;
  const float invN = 1.f / (float)N;

  u16* ws16 = (u16*)d_ws;
  u16* y16   = ws16;                       // N*64 f16 (y1, then y3)
  u16* v16   = y16 + (size_t)N*64;         // N*64 f16
  u16* mx16  = v16 + (size_t)N*64;         // N*64 f16
  u16* hw16  = mx16 + (size_t)N*64;        // N*8 f16
  uint4* fr  = (uint4*)(hw16 + (size_t)N*8);  // frag buffers (contiguous)
  uint4* wwf  = fr;                        // 128 uint4
  uint4* wp2f = fr + 128;                  // 512 uint4
  uint4* w1f  = fr + 640;                  // 384 uint4
  float* partials = (float*)(fr + 1024);   // 128*PST f32
  float* ss1      = partials + (size_t)128*PST;
  float* ss2      = ss1 + 128;
  float* ss3      = ss2 + 128;

  gemm_mfma_k<0, false><<<GRID_GEMM + 1, 256, 0, stream>>>(
      x, W1, Ww, nullptr, y16, nullptr, partials, N, Wp2, Wp1, wwf, wp2f, w1f);
  fin_k<<<64, 256, 0, stream>>>(partials, GRID_GEMM, g1, b1, ss1, invN);
  gemm_mfma_k<1, true><<<GRID_GEMM, 256, 0, stream>>>(
      y16, Wv, Ww, ss1, v16, hw16, nullptr, N, nullptr, nullptr, nullptr, nullptr, nullptr);
  mixer_k<<<GRID_MIX, 256, 0, stream>>>(p, knn, v16, hw16, fr, mx16, partials, N);
  fin_k<<<64, 256, 0, stream>>>(partials, GRID_MIX, g2, b2, ss2, invN);
  gemm_mfma_k<2, true><<<GRID_GEMM, 256, 0, stream>>>(
      mx16, W3, nullptr, ss2, y16, nullptr, partials, N, nullptr, nullptr, nullptr, nullptr, nullptr);
  fin_k<<<64, 256, 0, stream>>>(partials, GRID_GEMM, g3, b3, ss3, invN);
  final_k<<<GRID_ELT, 256, 0, stream>>>(y16, x, ss3, (float*)d_out, N*16);
}

// Round 13
// 126.157 us; speedup vs baseline: 2.2350x; 1.0687x over previous
//
#include <hip/hip_runtime.h>
#include <hip/hip_fp16.h>

#define EPSV 1e-5f
#define PST 2048
#define GRID_GEMM 1563
#define GRID_MIX  2048
#define GRID_ELT  2048

typedef _Float16 h2_t  __attribute__((ext_vector_type(2)));  // packed arithmetic
typedef __fp16   fp16x2 __attribute__((ext_vector_type(2))); // builtin interop
typedef _Float16 f16x4 __attribute__((ext_vector_type(4)));  // MFMA K=16 A/B frag
typedef _Float16 f16x8 __attribute__((ext_vector_type(8)));  // MFMA K=32 A/B frag
typedef float    f32x4 __attribute__((ext_vector_type(4)));  // MFMA C/D frag
typedef unsigned short u16;

__device__ __forceinline__ float frelu(float x) { return fmaxf(x, 0.f); }

__device__ __forceinline__ unsigned int pkrtz(float lo, float hi) {
  fp16x2 h = __builtin_amdgcn_cvt_pkrtz(lo, hi);
  return __builtin_bit_cast(unsigned int, h);
}
__device__ __forceinline__ u16 f16b(float x) {
  return (u16)(pkrtz(x, 0.f) & 0xffffu);
}
__device__ __forceinline__ float f16tof(u16 u) {
  return (float)(*reinterpret_cast<const _Float16*>(&u));
}
__device__ __forceinline__ f16x8 mk8(unsigned a, unsigned b, unsigned c, unsigned d) {
  uint4 u; u.x = a; u.y = b; u.z = c; u.w = d;
  return __builtin_bit_cast(f16x8, u);
}
__device__ __forceinline__ f16x4 mk4(unsigned a, unsigned b) {
  uint2 u; u.x = a; u.y = b;
  return __builtin_bit_cast(f16x4, u);
}
__device__ __forceinline__ f32x4 mfma16(f16x8 a, f16x8 b, f32x4 c) {
  return __builtin_amdgcn_mfma_f32_16x16x32_f16(a, b, c, 0, 0, 0);
}
__device__ __forceinline__ f32x4 mfma16k16(f16x4 a, f16x4 b, f32x4 c) {
  return __builtin_amdgcn_mfma_f32_16x16x16f16(a, b, c, 0, 0, 0);
}
// packed f16 relu via sign-bit masking
__device__ __forceinline__ unsigned relu2(unsigned u) {
  const unsigned m = ((u & 0x80008000u) >> 15) * 0xFFFFu;
  return u & ~m;
}

// ---------------------------------------------------------------------------
// MFMA f16 GEMM: out16[N,64](f16) = preop(in) @ W.
// MODE0 additionally: last block packs ww/wp2/wp1 fragment buffers (then exits).
template<int MODE, bool INF16>
__global__ __launch_bounds__(256, 4) void gemm_mfma_k(
    const void* __restrict__ in, const float* __restrict__ W,
    const float* __restrict__ Ww, const float* __restrict__ ss,
    u16* __restrict__ out16, u16* __restrict__ outw16,
    float* __restrict__ partials, int N,
    const float* __restrict__ Wp2, const float* __restrict__ Wp1,
    uint4* __restrict__ wwf, uint4* __restrict__ wp2f, uint4* __restrict__ w1f)
{
  __shared__ float red[512];
  __shared__ u16 xh[4][16*72];
  const int t = threadIdx.x, lane = t & 63, w = t >> 6;
  const int r16 = lane & 15, q = lane >> 4;

  if (MODE == 0 && blockIdx.x == GRID_GEMM) {
    float* wwl = (float*)&xh[0][0];   // 512 floats
    {
      const int a = t >> 2, qq = t & 3;
      float acc[8] = {0,0,0,0,0,0,0,0};
#pragma unroll
      for (int cc = 0; cc < 16; ++cc) {
        const int c = qq*16 + cc;
        const float wv = Wp2[a*64 + c];
#pragma unroll
        for (int g = 0; g < 8; ++g) acc[g] = fmaf(wv, Ww[c*8 + g], acc[g]);
      }
#pragma unroll
      for (int g = 0; g < 8; ++g) {
        acc[g] += __shfl_xor(acc[g], 1);
        acc[g] += __shfl_xor(acc[g], 2);
      }
      if (qq == 0) {
#pragma unroll
        for (int g = 0; g < 8; ++g) wwl[a*8 + g] = acc[g];
      }
    }
    __syncthreads();
    if (t < 128) {
      const int h = t >> 6, l = t & 63, rr = l & 15, qq = l >> 4;
      uint4 u = {0,0,0,0};
      if (rr < 8) {
        u.x = pkrtz(wwl[(32*h+8*qq+0)*8 + rr], wwl[(32*h+8*qq+1)*8 + rr]);
        u.y = pkrtz(wwl[(32*h+8*qq+2)*8 + rr], wwl[(32*h+8*qq+3)*8 + rr]);
        u.z = pkrtz(wwl[(32*h+8*qq+4)*8 + rr], wwl[(32*h+8*qq+5)*8 + rr]);
        u.w = pkrtz(wwl[(32*h+8*qq+6)*8 + rr], wwl[(32*h+8*qq+7)*8 + rr]);
      }
      wwf[t] = u;
    }
    for (int e = t; e < 512; e += 256) {
      const int tt = e >> 7, h = (e >> 6) & 1, l = e & 63;
      const int c = 16*tt + (l & 15), qq = l >> 4;
      const int d0 = 32*h + 8*qq;
      uint4 u;
      u.x = pkrtz(Wp2[(d0+0)*64 + c], Wp2[(d0+1)*64 + c]);
      u.y = pkrtz(Wp2[(d0+2)*64 + c], Wp2[(d0+3)*64 + c]);
      u.z = pkrtz(Wp2[(d0+4)*64 + c], Wp2[(d0+5)*64 + c]);
      u.w = pkrtz(Wp2[(d0+6)*64 + c], Wp2[(d0+7)*64 + c]);
      wp2f[e] = u;
    }
    for (int e = t; e < 384; e += 256) {
      const int r = e >> 7, h = (e >> 6) & 1, l = e & 63, qq = l >> 4;
      const int d0 = 32*h + 8*qq;
      uint4 u;
      u.x = pkrtz(Wp1[r*64 + d0+0], Wp1[r*64 + d0+1]);
      u.y = pkrtz(Wp1[r*64 + d0+2], Wp1[r*64 + d0+3]);
      u.z = pkrtz(Wp1[r*64 + d0+4], Wp1[r*64 + d0+5]);
      u.w = pkrtz(Wp1[r*64 + d0+6], Wp1[r*64 + d0+7]);
      w1f[e] = u;
    }
    return;
  }

  u16* const xw = &xh[w][0];
  f16x8 bw[2][4];
#pragma unroll
  for (int kb = 0; kb < 2; ++kb) {
#pragma unroll
    for (int tt = 0; tt < 4; ++tt) {
      const int kbase = 32*kb + 8*q;
      const int cc = 16*tt + r16;
      unsigned u0 = pkrtz(W[(kbase+0)*64 + cc], W[(kbase+1)*64 + cc]);
      unsigned u1 = pkrtz(W[(kbase+2)*64 + cc], W[(kbase+3)*64 + cc]);
      unsigned u2 = pkrtz(W[(kbase+4)*64 + cc], W[(kbase+5)*64 + cc]);
      unsigned u3 = pkrtz(W[(kbase+6)*64 + cc], W[(kbase+7)*64 + cc]);
      bw[kb][tt] = mk8(u0, u1, u2, u3);
    }
  }
  f16x8 bg[2];
  if (MODE == 1) {
#pragma unroll
    for (int kb = 0; kb < 2; ++kb) {
      const int kbase = 32*kb + 8*q;
      unsigned u[4];
#pragma unroll
      for (int mm = 0; mm < 4; ++mm) {
        float g0 = (r16 < 8) ? Ww[(kbase + 2*mm    )*8 + r16] : 0.f;
        float g1 = (r16 < 8) ? Ww[(kbase + 2*mm + 1)*8 + r16] : 0.f;
        u[mm] = pkrtz(g0, g1);
      }
      bg[kb] = mk8(u[0], u[1], u[2], u[3]);
    }
  }
  float sc4[4], sh4[4];
  if (MODE != 0) {
#pragma unroll
    for (int j = 0; j < 4; ++j) {
      sc4[j] = ss[4*r16 + j];
      sh4[j] = ss[64 + 4*r16 + j];
    }
  }

  float S4[4] = {0,0,0,0}, Q4[4] = {0,0,0,0};
  const int ntiles = (N + 15) >> 4;
  for (int tile = blockIdx.x*4 + w; tile < ntiles; tile += GRID_GEMM*4) {
    const int r0 = tile << 4;
    const bool full = (r0 + 16 <= N);
#pragma unroll
    for (int i = 0; i < 4; ++i) {
      const int row = q + 4*i;
      float4 xv = {0.f, 0.f, 0.f, 0.f};
      const bool rok = full || (r0 + row < N);
      if (rok) {
        if constexpr (INF16) {
          const uint2 u = *(const uint2*)((const u16*)in + (size_t)(r0 + row)*64 + 4*r16);
          const h2_t lo = __builtin_bit_cast(h2_t, u.x);
          const h2_t hi = __builtin_bit_cast(h2_t, u.y);
          xv.x = (float)lo[0]; xv.y = (float)lo[1];
          xv.z = (float)hi[0]; xv.w = (float)hi[1];
        } else {
          xv = *(const float4*)((const float*)in + (size_t)(r0 + row)*64 + 4*r16);
        }
      }
      if (MODE != 0) {
        xv.x = frelu(fmaf(xv.x, sc4[0], sh4[0]));
        xv.y = frelu(fmaf(xv.y, sc4[1], sh4[1]));
        xv.z = frelu(fmaf(xv.z, sc4[2], sh4[2]));
        xv.w = frelu(fmaf(xv.w, sc4[3], sh4[3]));
        if (!rok) { xv.x = 0.f; xv.y = 0.f; xv.z = 0.f; xv.w = 0.f; }
      }
      uint2 u2v; u2v.x = pkrtz(xv.x, xv.y); u2v.y = pkrtz(xv.z, xv.w);
      *(uint2*)(xw + row*72 + 4*r16) = u2v;
    }
    const f16x8 a0 = __builtin_bit_cast(f16x8, *(const uint4*)(xw + r16*72 + 8*q));
    const f16x8 a1 = __builtin_bit_cast(f16x8, *(const uint4*)(xw + r16*72 + 8*q + 32));
    f32x4 acc[4];
#pragma unroll
    for (int tt = 0; tt < 4; ++tt) {
      f32x4 z = {0.f, 0.f, 0.f, 0.f};
      z = mfma16(a0, bw[0][tt], z);
      acc[tt] = mfma16(a1, bw[1][tt], z);
    }
#pragma unroll
    for (int tt = 0; tt < 4; ++tt) {
#pragma unroll
      for (int j = 0; j < 4; ++j) {
        if (full || (r0 + 4*q + j < N))
          out16[(size_t)(r0 + 4*q + j)*64 + 16*tt + r16] = f16b(acc[tt][j]);
      }
      if (MODE != 1) {
        S4[tt] += acc[tt][0] + acc[tt][1] + acc[tt][2] + acc[tt][3];
        Q4[tt] = fmaf(acc[tt][0], acc[tt][0], Q4[tt]);
        Q4[tt] = fmaf(acc[tt][1], acc[tt][1], Q4[tt]);
        Q4[tt] = fmaf(acc[tt][2], acc[tt][2], Q4[tt]);
        Q4[tt] = fmaf(acc[tt][3], acc[tt][3], Q4[tt]);
      }
    }
    if (MODE == 1) {
      f32x4 accw = {0.f, 0.f, 0.f, 0.f};
      accw = mfma16(a0, bg[0], accw);
      accw = mfma16(a1, bg[1], accw);
      if (r16 < 8) {
#pragma unroll
        for (int j = 0; j < 4; ++j) {
          if (full || (r0 + 4*q + j < N))
            outw16[(size_t)(r0 + 4*q + j)*8 + r16] = f16b(accw[j]);
        }
      }
    }
  }
  if (MODE != 1) {
#pragma unroll
    for (int tt = 0; tt < 4; ++tt) {
      S4[tt] += __shfl_xor(S4[tt], 16); S4[tt] += __shfl_xor(S4[tt], 32);
      Q4[tt] += __shfl_xor(Q4[tt], 16); Q4[tt] += __shfl_xor(Q4[tt], 32);
    }
    if (lane < 16) {
#pragma unroll
      for (int tt = 0; tt < 4; ++tt) {
        red[w*128 + tt*16 + lane]      = S4[tt];
        red[w*128 + 64 + tt*16 + lane] = Q4[tt];
      }
    }
    __syncthreads();
    if (t < 64) {
      const float s = red[t] + red[128+t] + red[256+t] + red[384+t];
      const float qq = red[64+t] + red[192+t] + red[320+t] + red[448+t];
      partials[(size_t)t*PST + blockIdx.x]      = s;
      partials[(size_t)(64+t)*PST + blockIdx.x] = qq;
    }
  }
}

// ---------------------------------------------------------------------------
__global__ __launch_bounds__(256) void fin_k(const float* __restrict__ partials,
    int nblk, const float* __restrict__ gamma, const float* __restrict__ beta,
    float* __restrict__ ss, float invN)
{
  __shared__ float red[8];
  const int c = blockIdx.x;
  float s = 0.f, q = 0.f;
  for (int i = threadIdx.x; i < nblk; i += 256) {
    s += partials[(size_t)c*PST + i];
    q += partials[(size_t)(64+c)*PST + i];
  }
#pragma unroll
  for (int mk = 1; mk < 64; mk <<= 1) {
    s += __shfl_xor(s, mk);
    q += __shfl_xor(q, mk);
  }
  const int w = threadIdx.x >> 6;
  if ((threadIdx.x & 63) == 0) { red[w*2] = s; red[w*2+1] = q; }
  __syncthreads();
  if (threadIdx.x == 0) {
    const float S = red[0]+red[2]+red[4]+red[6];
    const float Q = red[1]+red[3]+red[5]+red[7];
    const float mean = S*invN;
    const float var  = Q*invN - mean*mean;
    const float scale = gamma[c] * rsqrtf(var + EPSV);
    ss[c] = scale; ss[64+c] = beta[c] - mean*scale;
  }
}

// ---------------------------------------------------------------------------
// MFMA mixer v3: R8 structure (constants in VGPR, (256,4) — best measured:
// 66us, no spill) + one-point-ahead kn/delta software prefetch to cut the
// knn->p serial round-trip out of the per-point critical path.
__global__ __launch_bounds__(256, 4) void mixer_k(
    const float* __restrict__ p, const int* __restrict__ knn,
    const u16* __restrict__ v16, const u16* __restrict__ hw16,
    const uint4* __restrict__ frags,   // wwf[0:128] wp2f[128:640] w1f[640:1024]
    u16* __restrict__ mx16, float* __restrict__ partials, int N)
{
  __shared__ float red[512];
  const int t = threadIdx.x, lane = t & 63, w = t >> 6;
  const int r16 = lane & 15, q = lane >> 4, b = r16 >> 3;

  // constants in VGPRs (R8 layout)
  f16x8 wwB[2];
  wwB[0] = __builtin_bit_cast(f16x8, frags[lane]);
  wwB[1] = __builtin_bit_cast(f16x8, frags[64 + lane]);
  f16x8 wp2B[8];
#pragma unroll
  for (int e = 0; e < 8; ++e)
    wp2B[e] = __builtin_bit_cast(f16x8, frags[128 + e*64 + lane]);
  unsigned w1a[6][4];
#pragma unroll
  for (int e = 0; e < 6; ++e) {
    const uint4 u = frags[640 + e*64 + lane];
    w1a[e][0] = u.x; w1a[e][1] = u.y; w1a[e][2] = u.z; w1a[e][3] = u.w;
  }

  float ssum = 0.f, sq = 0.f;
  const int nwaves = gridDim.x * 4;

  int i = blockIdx.x*4 + w;
  int4 kn4 = {0,0,0,0};
  float dx = 0.f, dy = 0.f, dz = 0.f;
  if (i < N) {   // wave-uniform prologue prefetch
    kn4 = *(const int4*)(knn + (size_t)i*16 + 4*q);
    const int jj = knn[(size_t)i*16 + r16];
    dx = p[(size_t)jj*3]   - p[(size_t)i*3];
    dy = p[(size_t)jj*3+1] - p[(size_t)i*3+1];
    dz = p[(size_t)jj*3+2] - p[(size_t)i*3+2];
  }

  while (i < N) {
    const int inext = i + nwaves;
    // ---- current point's gathers: kn4 already resident, issue immediately
    const int kn[4] = {kn4.x, kn4.y, kn4.z, kn4.w};
    unsigned vtp[4][2];
#pragma unroll
    for (int tt = 0; tt < 4; ++tt) {
      const unsigned v0 = v16[(size_t)kn[0]*64 + 16*tt + r16];
      const unsigned v1 = v16[(size_t)kn[1]*64 + 16*tt + r16];
      const unsigned v2 = v16[(size_t)kn[2]*64 + 16*tt + r16];
      const unsigned v3 = v16[(size_t)kn[3]*64 + 16*tt + r16];
      vtp[tt][0] = v0 | (v1 << 16);
      vtp[tt][1] = v2 | (v3 << 16);
    }
    u16 hvu[4];
#pragma unroll
    for (int j = 0; j < 4; ++j) hvu[j] = hw16[(size_t)kn[j]*8 + r16];

    // ---- e' fragments from the prefetched deltas (no memory dependency)
    const h2_t dx2 = __builtin_bit_cast(h2_t, pkrtz(dx, dx));
    const h2_t dy2 = __builtin_bit_cast(h2_t, pkrtz(dy, dy));
    const h2_t dz2 = __builtin_bit_cast(h2_t, pkrtz(dz, dz));
    f16x8 eA[2];
#pragma unroll
    for (int h = 0; h < 2; ++h) {
      unsigned eu[4];
#pragma unroll
      for (int mm = 0; mm < 4; ++mm) {
        h2_t acc = dz2 * __builtin_bit_cast(h2_t, w1a[4+h][mm]);
        acc = dy2 * __builtin_bit_cast(h2_t, w1a[2+h][mm]) + acc;
        acc = dx2 * __builtin_bit_cast(h2_t, w1a[0+h][mm]) + acc;
        eu[mm] = relu2(__builtin_bit_cast(unsigned, acc));
      }
      eA[h] = mk8(eu[0], eu[1], eu[2], eu[3]);
    }

    // ---- prefetch NEXT point's kn + deltas (latency hides under MFMA below)
    int4 kn4n = {0,0,0,0};
    float dxn = 0.f, dyn = 0.f, dzn = 0.f;
    if (inext < N) {
      kn4n = *(const int4*)(knn + (size_t)inext*16 + 4*q);
      const int jjn = knn[(size_t)inext*16 + r16];
      dxn = p[(size_t)jjn*3]   - p[(size_t)inext*3];
      dyn = p[(size_t)jjn*3+1] - p[(size_t)inext*3+1];
      dzn = p[(size_t)jjn*3+2] - p[(size_t)inext*3+2];
    }

    // ---- energy[k][g] via MFMA + hw bias ----
    f32x4 en = {0.f, 0.f, 0.f, 0.f};
    en = mfma16(eA[0], wwB[0], en);
    en = mfma16(eA[1], wwB[1], en);
#pragma unroll
    for (int j = 0; j < 4; ++j)
      en[j] += (r16 < 8) ? f16tof(hvu[j]) : 0.f;

    // ---- softmax over k ----
    float m = fmaxf(fmaxf(en[0], en[1]), fmaxf(en[2], en[3]));
    m = fmaxf(m, __shfl_xor(m, 16));
    m = fmaxf(m, __shfl_xor(m, 32));
    const float e0 = __expf(en[0]-m), e1 = __expf(en[1]-m);
    const float e2 = __expf(en[2]-m), e3 = __expf(en[3]-m);
    float s = e0 + e1 + e2 + e3;
    s += __shfl_xor(s, 16);
    s += __shfl_xor(s, 32);
    const float rs = 1.f / s;
    const f16x4 aw = mk4(pkrtz(e0*rs, e1*rs), pkrtz(e2*rs, e3*rs));

    // ---- per c-tile: E = e'@Wp2; G = w@V + w@E; extract ----
    float outv = 0.f;
#pragma unroll
    for (int tt = 0; tt < 4; ++tt) {
      f32x4 E = {0.f, 0.f, 0.f, 0.f};
      E = mfma16(eA[0], wp2B[tt*2], E);
      E = mfma16(eA[1], wp2B[tt*2+1], E);
      const f16x4 bE = mk4(pkrtz(E[0], E[1]), pkrtz(E[2], E[3]));
      const f16x4 bV = mk4(vtp[tt][0], vtp[tt][1]);
      f32x4 G = {0.f, 0.f, 0.f, 0.f};
      G = mfma16k16(aw, bV, G);
      G = mfma16k16(aw, bE, G);
      const float sel = b ? G[(2*tt+1) & 3] : G[(2*tt) & 3];
      const float val = __shfl(sel, ((tt >= 2) ? 16 : 0) + r16);
      if (q == tt) outv = val;
    }
    mx16[(size_t)i*64 + lane] = f16b(outv);
    ssum += outv; sq = fmaf(outv, outv, sq);

    // rotate pipeline
    i = inext;
    kn4 = kn4n; dx = dxn; dy = dyn; dz = dzn;
  }
  __syncthreads();
  red[w*128 + lane] = ssum; red[w*128 + 64 + lane] = sq;
  __syncthreads();
  if (t < 64) {
    const float s = red[t] + red[128+t] + red[256+t] + red[384+t];
    const float qv = red[64+t] + red[192+t] + red[320+t] + red[448+t];
    partials[(size_t)t*PST + blockIdx.x]      = s;
    partials[(size_t)(64+t)*PST + blockIdx.x] = qv;
  }
}

// ---------------------------------------------------------------------------
__global__ __launch_bounds__(256) void final_k(const u16* __restrict__ y16,
    const float* __restrict__ x, const float* __restrict__ ss,
    float* __restrict__ out, int n4)
{
  __shared__ float sl[128];
  if (threadIdx.x < 128) sl[threadIdx.x] = ss[threadIdx.x];
  __syncthreads();
  for (int idx = blockIdx.x*256 + threadIdx.x; idx < n4; idx += gridDim.x*256) {
    const int cb = (idx & 15) << 2;
    const uint2 yu = *(const uint2*)(y16 + (size_t)idx*4);
    const h2_t ylo = __builtin_bit_cast(h2_t, yu.x);
    const h2_t yhi = __builtin_bit_cast(h2_t, yu.y);
    const float4 xx = ((const float4*)x)[idx];
    float4 o;
    o.x = frelu(fmaf((float)ylo[0], sl[cb],   sl[64+cb])   + xx.x);
    o.y = frelu(fmaf((float)ylo[1], sl[cb+1], sl[64+cb+1]) + xx.y);
    o.z = frelu(fmaf((float)yhi[0], sl[cb+2], sl[64+cb+2]) + xx.z);
    o.w = frelu(fmaf((float)yhi[1], sl[cb+3], sl[64+cb+3]) + xx.w);
    ((float4*)out)[idx] = o;
  }
}

// ---------------------------------------------------------------------------
extern "C" void kernel_launch(void* const* d_in, const int* in_sizes, int n_in,
                              void* d_out, int out_size, void* d_ws, size_t ws_size,
                              hipStream_t stream)
{
  (void)n_in; (void)out_size; (void)ws_size;
  const float* p   = (const float*)d_in[0];
  const float* x   = (const float*)d_in[1];
  const int*   knn = (const int*)  d_in[2];
  const float* W1  = (const float*)d_in[3];
  const float* Wv  = (const float*)d_in[4];
  const float* Wp1 = (const float*)d_in[5];
  const float* Wp2 = (const float*)d_in[6];
  const float* Ww  = (const float*)d_in[7];
  const float* W3  = (const float*)d_in[8];
  const float* g1  = (const float*)d_in[9];
  const float* b1  = (const float*)d_in[10];
  const float* g2  = (const float*)d_in[11];
  const float* b2  = (const float*)d_in[12];
  const float* g3  = (const float*)d_in[13];
  const float* b3  = (const float*)d_in[14];
  const int N = in_sizes[0] / 3;
  const float invN = 1.f / (float)N;

  u16* ws16 = (u16*)d_ws;
  u16* y16   = ws16;                       // N*64 f16 (y1, then y3)
  u16* v16   = y16 + (size_t)N*64;         // N*64 f16
  u16* mx16  = v16 + (size_t)N*64;         // N*64 f16
  u16* hw16  = mx16 + (size_t)N*64;        // N*8 f16
  uint4* fr  = (uint4*)(hw16 + (size_t)N*8);  // frag buffers (contiguous)
  uint4* wwf  = fr;                        // 128 uint4
  uint4* wp2f = fr + 128;                  // 512 uint4
  uint4* w1f  = fr + 640;                  // 384 uint4
  float* partials = (float*)(fr + 1024);   // 128*PST f32
  float* ss1      = partials + (size_t)128*PST;
  float* ss2      = ss1 + 128;
  float* ss3      = ss2 + 128;

  gemm_mfma_k<0, false><<<GRID_GEMM + 1, 256, 0, stream>>>(
      x, W1, Ww, nullptr, y16, nullptr, partials, N, Wp2, Wp1, wwf, wp2f, w1f);
  fin_k<<<64, 256, 0, stream>>>(partials, GRID_GEMM, g1, b1, ss1, invN);
  gemm_mfma_k<1, true><<<GRID_GEMM, 256, 0, stream>>>(
      y16, Wv, Ww, ss1, v16, hw16, nullptr, N, nullptr, nullptr, nullptr, nullptr, nullptr);
  mixer_k<<<GRID_MIX, 256, 0, stream>>>(p, knn, v16, hw16, fr, mx16, partials, N);
  fin_k<<<64, 256, 0, stream>>>(partials, GRID_MIX, g2, b2, ss2, invN);
  gemm_mfma_k<2, true><<<GRID_GEMM, 256, 0, stream>>>(
      mx16, W3, nullptr, ss2, y16, nullptr, partials, N, nullptr, nullptr, nullptr, nullptr, nullptr);
  fin_k<<<64, 256, 0, stream>>>(partials, GRID_GEMM, g3, b3, ss3, invN);
  final_k<<<GRID_ELT, 256, 0, stream>>>(y16, x, ss3, (float*)d_out, N*16);
}

// Round 14
// 121.738 us; speedup vs baseline: 2.3161x; 1.0363x over previous
//
#include <hip/hip_runtime.h>
#include <hip/hip_fp16.h>

#define EPSV 1e-5f
#define PST 2048
#define GRID_GEMM 1563
#define GRID_MIX  2048
#define GRID_ELT  2048

typedef _Float16 h2_t  __attribute__((ext_vector_type(2)));  // packed arithmetic
typedef __fp16   fp16x2 __attribute__((ext_vector_type(2))); // builtin interop
typedef _Float16 f16x4 __attribute__((ext_vector_type(4)));  // MFMA K=16 A/B frag
typedef _Float16 f16x8 __attribute__((ext_vector_type(8)));  // MFMA K=32 A/B frag
typedef float    f32x4 __attribute__((ext_vector_type(4)));  // MFMA C/D frag
typedef unsigned short u16;

__device__ __forceinline__ float frelu(float x) { return fmaxf(x, 0.f); }

__device__ __forceinline__ unsigned int pkrtz(float lo, float hi) {
  fp16x2 h = __builtin_amdgcn_cvt_pkrtz(lo, hi);
  return __builtin_bit_cast(unsigned int, h);
}
__device__ __forceinline__ u16 f16b(float x) {
  return (u16)(pkrtz(x, 0.f) & 0xffffu);
}
__device__ __forceinline__ float f16tof(u16 u) {
  return (float)(*reinterpret_cast<const _Float16*>(&u));
}
__device__ __forceinline__ f16x8 mk8(unsigned a, unsigned b, unsigned c, unsigned d) {
  uint4 u; u.x = a; u.y = b; u.z = c; u.w = d;
  return __builtin_bit_cast(f16x8, u);
}
__device__ __forceinline__ f16x4 mk4(unsigned a, unsigned b) {
  uint2 u; u.x = a; u.y = b;
  return __builtin_bit_cast(f16x4, u);
}
__device__ __forceinline__ f32x4 mfma16(f16x8 a, f16x8 b, f32x4 c) {
  return __builtin_amdgcn_mfma_f32_16x16x32_f16(a, b, c, 0, 0, 0);
}
__device__ __forceinline__ f32x4 mfma16k16(f16x4 a, f16x4 b, f32x4 c) {
  return __builtin_amdgcn_mfma_f32_16x16x16f16(a, b, c, 0, 0, 0);
}
// packed f16 relu via sign-bit masking
__device__ __forceinline__ unsigned relu2(unsigned u) {
  const unsigned m = ((u & 0x80008000u) >> 15) * 0xFFFFu;
  return u & ~m;
}

// ---------------------------------------------------------------------------
// MFMA f16 GEMM: out16[N,64](f16) = preop(in) @ W.
// MODE0 additionally: last block packs ww/wp2/wp1 fragment buffers (then exits).
// MODE1: out16 (=v16) stored in PERMUTED column order [row][(c&15)*4+(c>>4)]
//        so the mixer can gather 8B per neighbor row instead of 4x2B.
template<int MODE, bool INF16>
__global__ __launch_bounds__(256, 4) void gemm_mfma_k(
    const void* __restrict__ in, const float* __restrict__ W,
    const float* __restrict__ Ww, const float* __restrict__ ss,
    u16* __restrict__ out16, u16* __restrict__ outw16,
    float* __restrict__ partials, int N,
    const float* __restrict__ Wp2, const float* __restrict__ Wp1,
    uint4* __restrict__ wwf, uint4* __restrict__ wp2f, uint4* __restrict__ w1f)
{
  __shared__ float red[512];
  __shared__ u16 xh[4][16*72];
  const int t = threadIdx.x, lane = t & 63, w = t >> 6;
  const int r16 = lane & 15, q = lane >> 4;

  if (MODE == 0 && blockIdx.x == GRID_GEMM) {
    float* wwl = (float*)&xh[0][0];   // 512 floats
    {
      const int a = t >> 2, qq = t & 3;
      float acc[8] = {0,0,0,0,0,0,0,0};
#pragma unroll
      for (int cc = 0; cc < 16; ++cc) {
        const int c = qq*16 + cc;
        const float wv = Wp2[a*64 + c];
#pragma unroll
        for (int g = 0; g < 8; ++g) acc[g] = fmaf(wv, Ww[c*8 + g], acc[g]);
      }
#pragma unroll
      for (int g = 0; g < 8; ++g) {
        acc[g] += __shfl_xor(acc[g], 1);
        acc[g] += __shfl_xor(acc[g], 2);
      }
      if (qq == 0) {
#pragma unroll
        for (int g = 0; g < 8; ++g) wwl[a*8 + g] = acc[g];
      }
    }
    __syncthreads();
    if (t < 128) {
      const int h = t >> 6, l = t & 63, rr = l & 15, qq = l >> 4;
      uint4 u = {0,0,0,0};
      if (rr < 8) {
        u.x = pkrtz(wwl[(32*h+8*qq+0)*8 + rr], wwl[(32*h+8*qq+1)*8 + rr]);
        u.y = pkrtz(wwl[(32*h+8*qq+2)*8 + rr], wwl[(32*h+8*qq+3)*8 + rr]);
        u.z = pkrtz(wwl[(32*h+8*qq+4)*8 + rr], wwl[(32*h+8*qq+5)*8 + rr]);
        u.w = pkrtz(wwl[(32*h+8*qq+6)*8 + rr], wwl[(32*h+8*qq+7)*8 + rr]);
      }
      wwf[t] = u;
    }
    for (int e = t; e < 512; e += 256) {
      const int tt = e >> 7, h = (e >> 6) & 1, l = e & 63;
      const int c = 16*tt + (l & 15), qq = l >> 4;
      const int d0 = 32*h + 8*qq;
      uint4 u;
      u.x = pkrtz(Wp2[(d0+0)*64 + c], Wp2[(d0+1)*64 + c]);
      u.y = pkrtz(Wp2[(d0+2)*64 + c], Wp2[(d0+3)*64 + c]);
      u.z = pkrtz(Wp2[(d0+4)*64 + c], Wp2[(d0+5)*64 + c]);
      u.w = pkrtz(Wp2[(d0+6)*64 + c], Wp2[(d0+7)*64 + c]);
      wp2f[e] = u;
    }
    for (int e = t; e < 384; e += 256) {
      const int r = e >> 7, h = (e >> 6) & 1, l = e & 63, qq = l >> 4;
      const int d0 = 32*h + 8*qq;
      uint4 u;
      u.x = pkrtz(Wp1[r*64 + d0+0], Wp1[r*64 + d0+1]);
      u.y = pkrtz(Wp1[r*64 + d0+2], Wp1[r*64 + d0+3]);
      u.z = pkrtz(Wp1[r*64 + d0+4], Wp1[r*64 + d0+5]);
      u.w = pkrtz(Wp1[r*64 + d0+6], Wp1[r*64 + d0+7]);
      w1f[e] = u;
    }
    return;
  }

  u16* const xw = &xh[w][0];
  f16x8 bw[2][4];
#pragma unroll
  for (int kb = 0; kb < 2; ++kb) {
#pragma unroll
    for (int tt = 0; tt < 4; ++tt) {
      const int kbase = 32*kb + 8*q;
      const int cc = 16*tt + r16;
      unsigned u0 = pkrtz(W[(kbase+0)*64 + cc], W[(kbase+1)*64 + cc]);
      unsigned u1 = pkrtz(W[(kbase+2)*64 + cc], W[(kbase+3)*64 + cc]);
      unsigned u2 = pkrtz(W[(kbase+4)*64 + cc], W[(kbase+5)*64 + cc]);
      unsigned u3 = pkrtz(W[(kbase+6)*64 + cc], W[(kbase+7)*64 + cc]);
      bw[kb][tt] = mk8(u0, u1, u2, u3);
    }
  }
  f16x8 bg[2];
  if (MODE == 1) {
#pragma unroll
    for (int kb = 0; kb < 2; ++kb) {
      const int kbase = 32*kb + 8*q;
      unsigned u[4];
#pragma unroll
      for (int mm = 0; mm < 4; ++mm) {
        float g0 = (r16 < 8) ? Ww[(kbase + 2*mm    )*8 + r16] : 0.f;
        float g1 = (r16 < 8) ? Ww[(kbase + 2*mm + 1)*8 + r16] : 0.f;
        u[mm] = pkrtz(g0, g1);
      }
      bg[kb] = mk8(u[0], u[1], u[2], u[3]);
    }
  }
  float sc4[4], sh4[4];
  if (MODE != 0) {
#pragma unroll
    for (int j = 0; j < 4; ++j) {
      sc4[j] = ss[4*r16 + j];
      sh4[j] = ss[64 + 4*r16 + j];
    }
  }

  float S4[4] = {0,0,0,0}, Q4[4] = {0,0,0,0};
  const int ntiles = (N + 15) >> 4;
  for (int tile = blockIdx.x*4 + w; tile < ntiles; tile += GRID_GEMM*4) {
    const int r0 = tile << 4;
    const bool full = (r0 + 16 <= N);
#pragma unroll
    for (int i = 0; i < 4; ++i) {
      const int row = q + 4*i;
      float4 xv = {0.f, 0.f, 0.f, 0.f};
      const bool rok = full || (r0 + row < N);
      if (rok) {
        if constexpr (INF16) {
          const uint2 u = *(const uint2*)((const u16*)in + (size_t)(r0 + row)*64 + 4*r16);
          const h2_t lo = __builtin_bit_cast(h2_t, u.x);
          const h2_t hi = __builtin_bit_cast(h2_t, u.y);
          xv.x = (float)lo[0]; xv.y = (float)lo[1];
          xv.z = (float)hi[0]; xv.w = (float)hi[1];
        } else {
          xv = *(const float4*)((const float*)in + (size_t)(r0 + row)*64 + 4*r16);
        }
      }
      if (MODE != 0) {
        xv.x = frelu(fmaf(xv.x, sc4[0], sh4[0]));
        xv.y = frelu(fmaf(xv.y, sc4[1], sh4[1]));
        xv.z = frelu(fmaf(xv.z, sc4[2], sh4[2]));
        xv.w = frelu(fmaf(xv.w, sc4[3], sh4[3]));
        if (!rok) { xv.x = 0.f; xv.y = 0.f; xv.z = 0.f; xv.w = 0.f; }
      }
      uint2 u2v; u2v.x = pkrtz(xv.x, xv.y); u2v.y = pkrtz(xv.z, xv.w);
      *(uint2*)(xw + row*72 + 4*r16) = u2v;
    }
    const f16x8 a0 = __builtin_bit_cast(f16x8, *(const uint4*)(xw + r16*72 + 8*q));
    const f16x8 a1 = __builtin_bit_cast(f16x8, *(const uint4*)(xw + r16*72 + 8*q + 32));
    f32x4 acc[4];
#pragma unroll
    for (int tt = 0; tt < 4; ++tt) {
      f32x4 z = {0.f, 0.f, 0.f, 0.f};
      z = mfma16(a0, bw[0][tt], z);
      acc[tt] = mfma16(a1, bw[1][tt], z);
    }
    if (MODE == 1) {
      // permuted v16 store: [row][r16*4 + tt], one 8B store per j
#pragma unroll
      for (int j = 0; j < 4; ++j) {
        const int row = r0 + 4*q + j;
        if (full || row < N) {
          uint2 st;
          st.x = pkrtz(acc[0][j], acc[1][j]);
          st.y = pkrtz(acc[2][j], acc[3][j]);
          *(uint2*)(out16 + (size_t)row*64 + r16*4) = st;
        }
      }
    } else {
#pragma unroll
      for (int tt = 0; tt < 4; ++tt) {
#pragma unroll
        for (int j = 0; j < 4; ++j) {
          if (full || (r0 + 4*q + j < N))
            out16[(size_t)(r0 + 4*q + j)*64 + 16*tt + r16] = f16b(acc[tt][j]);
        }
        S4[tt] += acc[tt][0] + acc[tt][1] + acc[tt][2] + acc[tt][3];
        Q4[tt] = fmaf(acc[tt][0], acc[tt][0], Q4[tt]);
        Q4[tt] = fmaf(acc[tt][1], acc[tt][1], Q4[tt]);
        Q4[tt] = fmaf(acc[tt][2], acc[tt][2], Q4[tt]);
        Q4[tt] = fmaf(acc[tt][3], acc[tt][3], Q4[tt]);
      }
    }
    if (MODE == 1) {
      f32x4 accw = {0.f, 0.f, 0.f, 0.f};
      accw = mfma16(a0, bg[0], accw);
      accw = mfma16(a1, bg[1], accw);
      if (r16 < 8) {
#pragma unroll
        for (int j = 0; j < 4; ++j) {
          if (full || (r0 + 4*q + j < N))
            outw16[(size_t)(r0 + 4*q + j)*8 + r16] = f16b(accw[j]);
        }
      }
    }
  }
  if (MODE != 1) {
#pragma unroll
    for (int tt = 0; tt < 4; ++tt) {
      S4[tt] += __shfl_xor(S4[tt], 16); S4[tt] += __shfl_xor(S4[tt], 32);
      Q4[tt] += __shfl_xor(Q4[tt], 16); Q4[tt] += __shfl_xor(Q4[tt], 32);
    }
    if (lane < 16) {
#pragma unroll
      for (int tt = 0; tt < 4; ++tt) {
        red[w*128 + tt*16 + lane]      = S4[tt];
        red[w*128 + 64 + tt*16 + lane] = Q4[tt];
      }
    }
    __syncthreads();
    if (t < 64) {
      const float s = red[t] + red[128+t] + red[256+t] + red[384+t];
      const float qq = red[64+t] + red[192+t] + red[320+t] + red[448+t];
      partials[(size_t)t*PST + blockIdx.x]      = s;
      partials[(size_t)(64+t)*PST + blockIdx.x] = qq;
    }
  }
}

// ---------------------------------------------------------------------------
__global__ __launch_bounds__(256) void fin_k(const float* __restrict__ partials,
    int nblk, const float* __restrict__ gamma, const float* __restrict__ beta,
    float* __restrict__ ss, float invN)
{
  __shared__ float red[8];
  const int c = blockIdx.x;
  float s = 0.f, q = 0.f;
  for (int i = threadIdx.x; i < nblk; i += 256) {
    s += partials[(size_t)c*PST + i];
    q += partials[(size_t)(64+c)*PST + i];
  }
#pragma unroll
  for (int mk = 1; mk < 64; mk <<= 1) {
    s += __shfl_xor(s, mk);
    q += __shfl_xor(q, mk);
  }
  const int w = threadIdx.x >> 6;
  if ((threadIdx.x & 63) == 0) { red[w*2] = s; red[w*2+1] = q; }
  __syncthreads();
  if (threadIdx.x == 0) {
    const float S = red[0]+red[2]+red[4]+red[6];
    const float Q = red[1]+red[3]+red[5]+red[7];
    const float mean = S*invN;
    const float var  = Q*invN - mean*mean;
    const float scale = gamma[c] * rsqrtf(var + EPSV);
    ss[c] = scale; ss[64+c] = beta[c] - mean*scale;
  }
}

// ---------------------------------------------------------------------------
// MFMA mixer v4: R8 structure (constants in VGPR, (256,4), no prefetch —
// R13 showed prefetch -9%) + 8B permuted v-gathers (16 vmem -> 4 vmem).
__global__ __launch_bounds__(256, 4) void mixer_k(
    const float* __restrict__ p, const int* __restrict__ knn,
    const u16* __restrict__ v16, const u16* __restrict__ hw16,
    const uint4* __restrict__ frags,   // wwf[0:128] wp2f[128:640] w1f[640:1024]
    u16* __restrict__ mx16, float* __restrict__ partials, int N)
{
  __shared__ float red[512];
  const int t = threadIdx.x, lane = t & 63, w = t >> 6;
  const int r16 = lane & 15, q = lane >> 4, b = r16 >> 3;

  // constants in VGPRs (R8 layout)
  f16x8 wwB[2];
  wwB[0] = __builtin_bit_cast(f16x8, frags[lane]);
  wwB[1] = __builtin_bit_cast(f16x8, frags[64 + lane]);
  f16x8 wp2B[8];
#pragma unroll
  for (int e = 0; e < 8; ++e)
    wp2B[e] = __builtin_bit_cast(f16x8, frags[128 + e*64 + lane]);
  unsigned w1a[6][4];
#pragma unroll
  for (int e = 0; e < 6; ++e) {
    const uint4 u = frags[640 + e*64 + lane];
    w1a[e][0] = u.x; w1a[e][1] = u.y; w1a[e][2] = u.z; w1a[e][3] = u.w;
  }

  float ssum = 0.f, sq = 0.f;
  const int nwaves = gridDim.x * 4;

  for (int i = blockIdx.x*4 + w; i < N; i += nwaves) {
    // ---- gathers (vmem pipe, issued early) ----
    const int4 kn4 = *(const int4*)(knn + (size_t)i*16 + 4*q);
    const int kn[4] = {kn4.x, kn4.y, kn4.z, kn4.w};
    const int jj = knn[(size_t)i*16 + r16];
    uint2 vu[4];                       // permuted rows: 8B per neighbor
#pragma unroll
    for (int j = 0; j < 4; ++j)
      vu[j] = *(const uint2*)(v16 + (size_t)kn[j]*64 + r16*4);
    u16 hvu[4];
#pragma unroll
    for (int j = 0; j < 4; ++j) hvu[j] = hw16[(size_t)kn[j]*8 + r16];
    const float pix = p[(size_t)i*3], piy = p[(size_t)i*3+1], piz = p[(size_t)i*3+2];
    const float dx = p[(size_t)jj*3]   - pix;
    const float dy = p[(size_t)jj*3+1] - piy;
    const float dz = p[(size_t)jj*3+2] - piz;

    // reassemble V B-frags: vtp[tt] = (v[j0]|v[j1]<<16, v[j2]|v[j3]<<16)
    unsigned vtp[4][2];
    vtp[0][0] = (vu[0].x & 0xffffu) | (vu[1].x << 16);
    vtp[1][0] = (vu[0].x >> 16)     | (vu[1].x & 0xffff0000u);
    vtp[2][0] = (vu[0].y & 0xffffu) | (vu[1].y << 16);
    vtp[3][0] = (vu[0].y >> 16)     | (vu[1].y & 0xffff0000u);
    vtp[0][1] = (vu[2].x & 0xffffu) | (vu[3].x << 16);
    vtp[1][1] = (vu[2].x >> 16)     | (vu[3].x & 0xffff0000u);
    vtp[2][1] = (vu[2].y & 0xffffu) | (vu[3].y << 16);
    vtp[3][1] = (vu[2].y >> 16)     | (vu[3].y & 0xffff0000u);

    // ---- e' fragments (packed f16, zero LDS) ----
    const h2_t dx2 = __builtin_bit_cast(h2_t, pkrtz(dx, dx));
    const h2_t dy2 = __builtin_bit_cast(h2_t, pkrtz(dy, dy));
    const h2_t dz2 = __builtin_bit_cast(h2_t, pkrtz(dz, dz));
    f16x8 eA[2];
#pragma unroll
    for (int h = 0; h < 2; ++h) {
      unsigned eu[4];
#pragma unroll
      for (int mm = 0; mm < 4; ++mm) {
        h2_t acc = dz2 * __builtin_bit_cast(h2_t, w1a[4+h][mm]);
        acc = dy2 * __builtin_bit_cast(h2_t, w1a[2+h][mm]) + acc;
        acc = dx2 * __builtin_bit_cast(h2_t, w1a[0+h][mm]) + acc;
        eu[mm] = relu2(__builtin_bit_cast(unsigned, acc));
      }
      eA[h] = mk8(eu[0], eu[1], eu[2], eu[3]);
    }

    // ---- energy[k][g] via MFMA + hw bias ----
    f32x4 en = {0.f, 0.f, 0.f, 0.f};
    en = mfma16(eA[0], wwB[0], en);
    en = mfma16(eA[1], wwB[1], en);
#pragma unroll
    for (int j = 0; j < 4; ++j)
      en[j] += (r16 < 8) ? f16tof(hvu[j]) : 0.f;

    // ---- softmax over k ----
    float m = fmaxf(fmaxf(en[0], en[1]), fmaxf(en[2], en[3]));
    m = fmaxf(m, __shfl_xor(m, 16));
    m = fmaxf(m, __shfl_xor(m, 32));
    const float e0 = __expf(en[0]-m), e1 = __expf(en[1]-m);
    const float e2 = __expf(en[2]-m), e3 = __expf(en[3]-m);
    float s = e0 + e1 + e2 + e3;
    s += __shfl_xor(s, 16);
    s += __shfl_xor(s, 32);
    const float rs = 1.f / s;
    const f16x4 aw = mk4(pkrtz(e0*rs, e1*rs), pkrtz(e2*rs, e3*rs));

    // ---- per c-tile: E = e'@Wp2; G = w@V + w@E; extract ----
    float outv = 0.f;
#pragma unroll
    for (int tt = 0; tt < 4; ++tt) {
      f32x4 E = {0.f, 0.f, 0.f, 0.f};
      E = mfma16(eA[0], wp2B[tt*2], E);
      E = mfma16(eA[1], wp2B[tt*2+1], E);
      const f16x4 bE = mk4(pkrtz(E[0], E[1]), pkrtz(E[2], E[3]));
      const f16x4 bV = mk4(vtp[tt][0], vtp[tt][1]);
      f32x4 G = {0.f, 0.f, 0.f, 0.f};
      G = mfma16k16(aw, bV, G);
      G = mfma16k16(aw, bE, G);
      const float sel = b ? G[(2*tt+1) & 3] : G[(2*tt) & 3];
      const float val = __shfl(sel, ((tt >= 2) ? 16 : 0) + r16);
      if (q == tt) outv = val;
    }
    mx16[(size_t)i*64 + lane] = f16b(outv);
    ssum += outv; sq = fmaf(outv, outv, sq);
  }
  __syncthreads();
  red[w*128 + lane] = ssum; red[w*128 + 64 + lane] = sq;
  __syncthreads();
  if (t < 64) {
    const float s = red[t] + red[128+t] + red[256+t] + red[384+t];
    const float qv = red[64+t] + red[192+t] + red[320+t] + red[448+t];
    partials[(size_t)t*PST + blockIdx.x]      = s;
    partials[(size_t)(64+t)*PST + blockIdx.x] = qv;
  }
}

// ---------------------------------------------------------------------------
__global__ __launch_bounds__(256) void final_k(const u16* __restrict__ y16,
    const float* __restrict__ x, const float* __restrict__ ss,
    float* __restrict__ out, int n4)
{
  __shared__ float sl[128];
  if (threadIdx.x < 128) sl[threadIdx.x] = ss[threadIdx.x];
  __syncthreads();
  for (int idx = blockIdx.x*256 + threadIdx.x; idx < n4; idx += gridDim.x*256) {
    const int cb = (idx & 15) << 2;
    const uint2 yu = *(const uint2*)(y16 + (size_t)idx*4);
    const h2_t ylo = __builtin_bit_cast(h2_t, yu.x);
    const h2_t yhi = __builtin_bit_cast(h2_t, yu.y);
    const float4 xx = ((const float4*)x)[idx];
    float4 o;
    o.x = frelu(fmaf((float)ylo[0], sl[cb],   sl[64+cb])   + xx.x);
    o.y = frelu(fmaf((float)ylo[1], sl[cb+1], sl[64+cb+1]) + xx.y);
    o.z = frelu(fmaf((float)yhi[0], sl[cb+2], sl[64+cb+2]) + xx.z);
    o.w = frelu(fmaf((float)yhi[1], sl[cb+3], sl[64+cb+3]) + xx.w);
    ((float4*)out)[idx] = o;
  }
}

// ---------------------------------------------------------------------------
extern "C" void kernel_launch(void* const* d_in, const int* in_sizes, int n_in,
                              void* d_out, int out_size, void* d_ws, size_t ws_size,
                              hipStream_t stream)
{
  (void)n_in; (void)out_size; (void)ws_size;
  const float* p   = (const float*)d_in[0];
  const float* x   = (const float*)d_in[1];
  const int*   knn = (const int*)  d_in[2];
  const float* W1  = (const float*)d_in[3];
  const float* Wv  = (const float*)d_in[4];
  const float* Wp1 = (const float*)d_in[5];
  const float* Wp2 = (const float*)d_in[6];
  const float* Ww  = (const float*)d_in[7];
  const float* W3  = (const float*)d_in[8];
  const float* g1  = (const float*)d_in[9];
  const float* b1  = (const float*)d_in[10];
  const float* g2  = (const float*)d_in[11];
  const float* b2  = (const float*)d_in[12];
  const float* g3  = (const float*)d_in[13];
  const float* b3  = (const float*)d_in[14];
  const int N = in_sizes[0] / 3;
  const float invN = 1.f / (float)N;

  u16* ws16 = (u16*)d_ws;
  u16* y16   = ws16;                       // N*64 f16 (y1, then y3)
  u16* v16   = y16 + (size_t)N*64;         // N*64 f16 (PERMUTED col order)
  u16* mx16  = v16 + (size_t)N*64;         // N*64 f16
  u16* hw16  = mx16 + (size_t)N*64;        // N*8 f16
  uint4* fr  = (uint4*)(hw16 + (size_t)N*8);  // frag buffers (contiguous)
  uint4* wwf  = fr;                        // 128 uint4
  uint4* wp2f = fr + 128;                  // 512 uint4
  uint4* w1f  = fr + 640;                  // 384 uint4
  float* partials = (float*)(fr + 1024);   // 128*PST f32
  float* ss1      = partials + (size_t)128*PST;
  float* ss2      = ss1 + 128;
  float* ss3      = ss2 + 128;

  gemm_mfma_k<0, false><<<GRID_GEMM + 1, 256, 0, stream>>>(
      x, W1, Ww, nullptr, y16, nullptr, partials, N, Wp2, Wp1, wwf, wp2f, w1f);
  fin_k<<<64, 256, 0, stream>>>(partials, GRID_GEMM, g1, b1, ss1, invN);
  gemm_mfma_k<1, true><<<GRID_GEMM, 256, 0, stream>>>(
      y16, Wv, Ww, ss1, v16, hw16, nullptr, N, nullptr, nullptr, nullptr, nullptr, nullptr);
  mixer_k<<<GRID_MIX, 256, 0, stream>>>(p, knn, v16, hw16, fr, mx16, partials, N);
  fin_k<<<64, 256, 0, stream>>>(partials, GRID_MIX, g2, b2, ss2, invN);
  gemm_mfma_k<2, true><<<GRID_GEMM, 256, 0, stream>>>(
      mx16, W3, nullptr, ss2, y16, nullptr, partials, N, nullptr, nullptr, nullptr, nullptr, nullptr);
  fin_k<<<64, 256, 0, stream>>>(partials, GRID_GEMM, g3, b3, ss3, invN);
  final_k<<<GRID_ELT, 256, 0, stream>>>(y16, x, ss3, (float*)d_out, N*16);
}

// Round 15
// 120.826 us; speedup vs baseline: 2.3336x; 1.0075x over previous
//
#include <hip/hip_runtime.h>
#include <hip/hip_fp16.h>

#define EPSV 1e-5f
#define PST 2048
#define GRID_GEMM 1563
#define GRID_MIX  2048
#define GRID_ELT  2048

typedef _Float16 h2_t  __attribute__((ext_vector_type(2)));  // packed arithmetic
typedef __fp16   fp16x2 __attribute__((ext_vector_type(2))); // builtin interop
typedef _Float16 f16x4 __attribute__((ext_vector_type(4)));  // MFMA K=16 A/B frag
typedef _Float16 f16x8 __attribute__((ext_vector_type(8)));  // MFMA K=32 A/B frag
typedef float    f32x4 __attribute__((ext_vector_type(4)));  // MFMA C/D frag
typedef unsigned short u16;

__device__ __forceinline__ float frelu(float x) { return fmaxf(x, 0.f); }

__device__ __forceinline__ unsigned int pkrtz(float lo, float hi) {
  fp16x2 h = __builtin_amdgcn_cvt_pkrtz(lo, hi);
  return __builtin_bit_cast(unsigned int, h);
}
__device__ __forceinline__ u16 f16b(float x) {
  return (u16)(pkrtz(x, 0.f) & 0xffffu);
}
__device__ __forceinline__ float f16tof(u16 u) {
  return (float)(*reinterpret_cast<const _Float16*>(&u));
}
__device__ __forceinline__ f16x8 mk8(unsigned a, unsigned b, unsigned c, unsigned d) {
  uint4 u; u.x = a; u.y = b; u.z = c; u.w = d;
  return __builtin_bit_cast(f16x8, u);
}
__device__ __forceinline__ f16x4 mk4(unsigned a, unsigned b) {
  uint2 u; u.x = a; u.y = b;
  return __builtin_bit_cast(f16x4, u);
}
__device__ __forceinline__ f32x4 mfma16(f16x8 a, f16x8 b, f32x4 c) {
  return __builtin_amdgcn_mfma_f32_16x16x32_f16(a, b, c, 0, 0, 0);
}
__device__ __forceinline__ f32x4 mfma16k16(f16x4 a, f16x4 b, f32x4 c) {
  return __builtin_amdgcn_mfma_f32_16x16x16f16(a, b, c, 0, 0, 0);
}
// packed f16 relu via sign-bit masking
__device__ __forceinline__ unsigned relu2(unsigned u) {
  const unsigned m = ((u & 0x80008000u) >> 15) * 0xFFFFu;
  return u & ~m;
}

// ---------------------------------------------------------------------------
// MFMA f16 GEMM: out16[N,64](f16) = preop(in) @ W.
// MODE0 additionally: last block packs ww/wp2/wp1 fragment buffers (then exits).
// MODE1: out16 (=v16) stored in PERMUTED column order [row][(c&15)*4+(c>>4)].
template<int MODE, bool INF16>
__global__ __launch_bounds__(256, 4) void gemm_mfma_k(
    const void* __restrict__ in, const float* __restrict__ W,
    const float* __restrict__ Ww, const float* __restrict__ ss,
    u16* __restrict__ out16, u16* __restrict__ outw16,
    float* __restrict__ partials, int N,
    const float* __restrict__ Wp2, const float* __restrict__ Wp1,
    uint4* __restrict__ wwf, uint4* __restrict__ wp2f, uint4* __restrict__ w1f)
{
  __shared__ float red[512];
  __shared__ u16 xh[4][16*72];
  const int t = threadIdx.x, lane = t & 63, w = t >> 6;
  const int r16 = lane & 15, q = lane >> 4;

  if (MODE == 0 && blockIdx.x == GRID_GEMM) {
    float* wwl = (float*)&xh[0][0];   // 512 floats
    {
      const int a = t >> 2, qq = t & 3;
      float acc[8] = {0,0,0,0,0,0,0,0};
#pragma unroll
      for (int cc = 0; cc < 16; ++cc) {
        const int c = qq*16 + cc;
        const float wv = Wp2[a*64 + c];
#pragma unroll
        for (int g = 0; g < 8; ++g) acc[g] = fmaf(wv, Ww[c*8 + g], acc[g]);
      }
#pragma unroll
      for (int g = 0; g < 8; ++g) {
        acc[g] += __shfl_xor(acc[g], 1);
        acc[g] += __shfl_xor(acc[g], 2);
      }
      if (qq == 0) {
#pragma unroll
        for (int g = 0; g < 8; ++g) wwl[a*8 + g] = acc[g];
      }
    }
    __syncthreads();
    if (t < 128) {
      const int h = t >> 6, l = t & 63, rr = l & 15, qq = l >> 4;
      uint4 u = {0,0,0,0};
      if (rr < 8) {
        u.x = pkrtz(wwl[(32*h+8*qq+0)*8 + rr], wwl[(32*h+8*qq+1)*8 + rr]);
        u.y = pkrtz(wwl[(32*h+8*qq+2)*8 + rr], wwl[(32*h+8*qq+3)*8 + rr]);
        u.z = pkrtz(wwl[(32*h+8*qq+4)*8 + rr], wwl[(32*h+8*qq+5)*8 + rr]);
        u.w = pkrtz(wwl[(32*h+8*qq+6)*8 + rr], wwl[(32*h+8*qq+7)*8 + rr]);
      }
      wwf[t] = u;
    }
    for (int e = t; e < 512; e += 256) {
      const int tt = e >> 7, h = (e >> 6) & 1, l = e & 63;
      const int c = 16*tt + (l & 15), qq = l >> 4;
      const int d0 = 32*h + 8*qq;
      uint4 u;
      u.x = pkrtz(Wp2[(d0+0)*64 + c], Wp2[(d0+1)*64 + c]);
      u.y = pkrtz(Wp2[(d0+2)*64 + c], Wp2[(d0+3)*64 + c]);
      u.z = pkrtz(Wp2[(d0+4)*64 + c], Wp2[(d0+5)*64 + c]);
      u.w = pkrtz(Wp2[(d0+6)*64 + c], Wp2[(d0+7)*64 + c]);
      wp2f[e] = u;
    }
    for (int e = t; e < 384; e += 256) {
      const int r = e >> 7, h = (e >> 6) & 1, l = e & 63, qq = l >> 4;
      const int d0 = 32*h + 8*qq;
      uint4 u;
      u.x = pkrtz(Wp1[r*64 + d0+0], Wp1[r*64 + d0+1]);
      u.y = pkrtz(Wp1[r*64 + d0+2], Wp1[r*64 + d0+3]);
      u.z = pkrtz(Wp1[r*64 + d0+4], Wp1[r*64 + d0+5]);
      u.w = pkrtz(Wp1[r*64 + d0+6], Wp1[r*64 + d0+7]);
      w1f[e] = u;
    }
    return;
  }

  u16* const xw = &xh[w][0];
  f16x8 bw[2][4];
#pragma unroll
  for (int kb = 0; kb < 2; ++kb) {
#pragma unroll
    for (int tt = 0; tt < 4; ++tt) {
      const int kbase = 32*kb + 8*q;
      const int cc = 16*tt + r16;
      unsigned u0 = pkrtz(W[(kbase+0)*64 + cc], W[(kbase+1)*64 + cc]);
      unsigned u1 = pkrtz(W[(kbase+2)*64 + cc], W[(kbase+3)*64 + cc]);
      unsigned u2 = pkrtz(W[(kbase+4)*64 + cc], W[(kbase+5)*64 + cc]);
      unsigned u3 = pkrtz(W[(kbase+6)*64 + cc], W[(kbase+7)*64 + cc]);
      bw[kb][tt] = mk8(u0, u1, u2, u3);
    }
  }
  f16x8 bg[2];
  if (MODE == 1) {
#pragma unroll
    for (int kb = 0; kb < 2; ++kb) {
      const int kbase = 32*kb + 8*q;
      unsigned u[4];
#pragma unroll
      for (int mm = 0; mm < 4; ++mm) {
        float g0 = (r16 < 8) ? Ww[(kbase + 2*mm    )*8 + r16] : 0.f;
        float g1 = (r16 < 8) ? Ww[(kbase + 2*mm + 1)*8 + r16] : 0.f;
        u[mm] = pkrtz(g0, g1);
      }
      bg[kb] = mk8(u[0], u[1], u[2], u[3]);
    }
  }
  float sc4[4], sh4[4];
  if (MODE != 0) {
#pragma unroll
    for (int j = 0; j < 4; ++j) {
      sc4[j] = ss[4*r16 + j];
      sh4[j] = ss[64 + 4*r16 + j];
    }
  }

  float S4[4] = {0,0,0,0}, Q4[4] = {0,0,0,0};
  const int ntiles = (N + 15) >> 4;
  for (int tile = blockIdx.x*4 + w; tile < ntiles; tile += GRID_GEMM*4) {
    const int r0 = tile << 4;
    const bool full = (r0 + 16 <= N);
#pragma unroll
    for (int i = 0; i < 4; ++i) {
      const int row = q + 4*i;
      float4 xv = {0.f, 0.f, 0.f, 0.f};
      const bool rok = full || (r0 + row < N);
      if (rok) {
        if constexpr (INF16) {
          const uint2 u = *(const uint2*)((const u16*)in + (size_t)(r0 + row)*64 + 4*r16);
          const h2_t lo = __builtin_bit_cast(h2_t, u.x);
          const h2_t hi = __builtin_bit_cast(h2_t, u.y);
          xv.x = (float)lo[0]; xv.y = (float)lo[1];
          xv.z = (float)hi[0]; xv.w = (float)hi[1];
        } else {
          xv = *(const float4*)((const float*)in + (size_t)(r0 + row)*64 + 4*r16);
        }
      }
      if (MODE != 0) {
        xv.x = frelu(fmaf(xv.x, sc4[0], sh4[0]));
        xv.y = frelu(fmaf(xv.y, sc4[1], sh4[1]));
        xv.z = frelu(fmaf(xv.z, sc4[2], sh4[2]));
        xv.w = frelu(fmaf(xv.w, sc4[3], sh4[3]));
        if (!rok) { xv.x = 0.f; xv.y = 0.f; xv.z = 0.f; xv.w = 0.f; }
      }
      uint2 u2v; u2v.x = pkrtz(xv.x, xv.y); u2v.y = pkrtz(xv.z, xv.w);
      *(uint2*)(xw + row*72 + 4*r16) = u2v;
    }
    const f16x8 a0 = __builtin_bit_cast(f16x8, *(const uint4*)(xw + r16*72 + 8*q));
    const f16x8 a1 = __builtin_bit_cast(f16x8, *(const uint4*)(xw + r16*72 + 8*q + 32));
    f32x4 acc[4];
#pragma unroll
    for (int tt = 0; tt < 4; ++tt) {
      f32x4 z = {0.f, 0.f, 0.f, 0.f};
      z = mfma16(a0, bw[0][tt], z);
      acc[tt] = mfma16(a1, bw[1][tt], z);
    }
    if (MODE == 1) {
      // permuted v16 store: [row][r16*4 + tt], one 8B store per j
#pragma unroll
      for (int j = 0; j < 4; ++j) {
        const int row = r0 + 4*q + j;
        if (full || row < N) {
          uint2 st;
          st.x = pkrtz(acc[0][j], acc[1][j]);
          st.y = pkrtz(acc[2][j], acc[3][j]);
          *(uint2*)(out16 + (size_t)row*64 + r16*4) = st;
        }
      }
    } else {
#pragma unroll
      for (int tt = 0; tt < 4; ++tt) {
#pragma unroll
        for (int j = 0; j < 4; ++j) {
          if (full || (r0 + 4*q + j < N))
            out16[(size_t)(r0 + 4*q + j)*64 + 16*tt + r16] = f16b(acc[tt][j]);
        }
        S4[tt] += acc[tt][0] + acc[tt][1] + acc[tt][2] + acc[tt][3];
        Q4[tt] = fmaf(acc[tt][0], acc[tt][0], Q4[tt]);
        Q4[tt] = fmaf(acc[tt][1], acc[tt][1], Q4[tt]);
        Q4[tt] = fmaf(acc[tt][2], acc[tt][2], Q4[tt]);
        Q4[tt] = fmaf(acc[tt][3], acc[tt][3], Q4[tt]);
      }
    }
    if (MODE == 1) {
      f32x4 accw = {0.f, 0.f, 0.f, 0.f};
      accw = mfma16(a0, bg[0], accw);
      accw = mfma16(a1, bg[1], accw);
      if (r16 < 8) {
#pragma unroll
        for (int j = 0; j < 4; ++j) {
          if (full || (r0 + 4*q + j < N))
            outw16[(size_t)(r0 + 4*q + j)*8 + r16] = f16b(accw[j]);
        }
      }
    }
  }
  if (MODE != 1) {
#pragma unroll
    for (int tt = 0; tt < 4; ++tt) {
      S4[tt] += __shfl_xor(S4[tt], 16); S4[tt] += __shfl_xor(S4[tt], 32);
      Q4[tt] += __shfl_xor(Q4[tt], 16); Q4[tt] += __shfl_xor(Q4[tt], 32);
    }
    if (lane < 16) {
#pragma unroll
      for (int tt = 0; tt < 4; ++tt) {
        red[w*128 + tt*16 + lane]      = S4[tt];
        red[w*128 + 64 + tt*16 + lane] = Q4[tt];
      }
    }
    __syncthreads();
    if (t < 64) {
      const float s = red[t] + red[128+t] + red[256+t] + red[384+t];
      const float qq = red[64+t] + red[192+t] + red[320+t] + red[448+t];
      partials[(size_t)t*PST + blockIdx.x]      = s;
      partials[(size_t)(64+t)*PST + blockIdx.x] = qq;
    }
  }
}

// ---------------------------------------------------------------------------
__global__ __launch_bounds__(256) void fin_k(const float* __restrict__ partials,
    int nblk, const float* __restrict__ gamma, const float* __restrict__ beta,
    float* __restrict__ ss, float invN)
{
  __shared__ float red[8];
  const int c = blockIdx.x;
  float s = 0.f, q = 0.f;
  for (int i = threadIdx.x; i < nblk; i += 256) {
    s += partials[(size_t)c*PST + i];
    q += partials[(size_t)(64+c)*PST + i];
  }
#pragma unroll
  for (int mk = 1; mk < 64; mk <<= 1) {
    s += __shfl_xor(s, mk);
    q += __shfl_xor(q, mk);
  }
  const int w = threadIdx.x >> 6;
  if ((threadIdx.x & 63) == 0) { red[w*2] = s; red[w*2+1] = q; }
  __syncthreads();
  if (threadIdx.x == 0) {
    const float S = red[0]+red[2]+red[4]+red[6];
    const float Q = red[1]+red[3]+red[5]+red[7];
    const float mean = S*invN;
    const float var  = Q*invN - mean*mean;
    const float scale = gamma[c] * rsqrtf(var + EPSV);
    ss[c] = scale; ss[64+c] = beta[c] - mean*scale;
  }
}

// ---------------------------------------------------------------------------
// MFMA mixer v5: R14 structure + 2-point-per-iteration in-wave ILP.
// Both points' gather chains issue up front; B's memory latency drains
// under A's ~330cyc compute (and A's under prev-B's). (256,4) budget held
// spill-free at R8 with comparable live state; WRITE_SIZE is the tripwire.
__global__ __launch_bounds__(256, 4) void mixer_k(
    const float* __restrict__ p, const int* __restrict__ knn,
    const u16* __restrict__ v16, const u16* __restrict__ hw16,
    const uint4* __restrict__ frags,   // wwf[0:128] wp2f[128:640] w1f[640:1024]
    u16* __restrict__ mx16, float* __restrict__ partials, int N)
{
  __shared__ float red[512];
  const int t = threadIdx.x, lane = t & 63, w = t >> 6;
  const int r16 = lane & 15, q = lane >> 4, b = r16 >> 3;

  // constants in VGPRs (R8 layout)
  f16x8 wwB[2];
  wwB[0] = __builtin_bit_cast(f16x8, frags[lane]);
  wwB[1] = __builtin_bit_cast(f16x8, frags[64 + lane]);
  f16x8 wp2B[8];
#pragma unroll
  for (int e = 0; e < 8; ++e)
    wp2B[e] = __builtin_bit_cast(f16x8, frags[128 + e*64 + lane]);
  unsigned w1a[6][4];
#pragma unroll
  for (int e = 0; e < 6; ++e) {
    const uint4 u = frags[640 + e*64 + lane];
    w1a[e][0] = u.x; w1a[e][1] = u.y; w1a[e][2] = u.z; w1a[e][3] = u.w;
  }

  float ssum = 0.f, sq = 0.f;
  const int nwaves = gridDim.x * 4;

  // per-point compute: from gathered (vu, hvu, deltas) -> mixed value
  auto computePoint = [&](const uint2* vu, const u16* hvu,
                          float dx, float dy, float dz) -> float {
    unsigned vtp[4][2];
    vtp[0][0] = (vu[0].x & 0xffffu) | (vu[1].x << 16);
    vtp[1][0] = (vu[0].x >> 16)     | (vu[1].x & 0xffff0000u);
    vtp[2][0] = (vu[0].y & 0xffffu) | (vu[1].y << 16);
    vtp[3][0] = (vu[0].y >> 16)     | (vu[1].y & 0xffff0000u);
    vtp[0][1] = (vu[2].x & 0xffffu) | (vu[3].x << 16);
    vtp[1][1] = (vu[2].x >> 16)     | (vu[3].x & 0xffff0000u);
    vtp[2][1] = (vu[2].y & 0xffffu) | (vu[3].y << 16);
    vtp[3][1] = (vu[2].y >> 16)     | (vu[3].y & 0xffff0000u);

    const h2_t dx2 = __builtin_bit_cast(h2_t, pkrtz(dx, dx));
    const h2_t dy2 = __builtin_bit_cast(h2_t, pkrtz(dy, dy));
    const h2_t dz2 = __builtin_bit_cast(h2_t, pkrtz(dz, dz));
    f16x8 eA[2];
#pragma unroll
    for (int h = 0; h < 2; ++h) {
      unsigned eu[4];
#pragma unroll
      for (int mm = 0; mm < 4; ++mm) {
        h2_t acc = dz2 * __builtin_bit_cast(h2_t, w1a[4+h][mm]);
        acc = dy2 * __builtin_bit_cast(h2_t, w1a[2+h][mm]) + acc;
        acc = dx2 * __builtin_bit_cast(h2_t, w1a[0+h][mm]) + acc;
        eu[mm] = relu2(__builtin_bit_cast(unsigned, acc));
      }
      eA[h] = mk8(eu[0], eu[1], eu[2], eu[3]);
    }

    f32x4 en = {0.f, 0.f, 0.f, 0.f};
    en = mfma16(eA[0], wwB[0], en);
    en = mfma16(eA[1], wwB[1], en);
#pragma unroll
    for (int j = 0; j < 4; ++j)
      en[j] += (r16 < 8) ? f16tof(hvu[j]) : 0.f;

    float m = fmaxf(fmaxf(en[0], en[1]), fmaxf(en[2], en[3]));
    m = fmaxf(m, __shfl_xor(m, 16));
    m = fmaxf(m, __shfl_xor(m, 32));
    const float e0 = __expf(en[0]-m), e1 = __expf(en[1]-m);
    const float e2 = __expf(en[2]-m), e3 = __expf(en[3]-m);
    float s = e0 + e1 + e2 + e3;
    s += __shfl_xor(s, 16);
    s += __shfl_xor(s, 32);
    const float rs = 1.f / s;
    const f16x4 aw = mk4(pkrtz(e0*rs, e1*rs), pkrtz(e2*rs, e3*rs));

    float outv = 0.f;
#pragma unroll
    for (int tt = 0; tt < 4; ++tt) {
      f32x4 E = {0.f, 0.f, 0.f, 0.f};
      E = mfma16(eA[0], wp2B[tt*2], E);
      E = mfma16(eA[1], wp2B[tt*2+1], E);
      const f16x4 bE = mk4(pkrtz(E[0], E[1]), pkrtz(E[2], E[3]));
      const f16x4 bV = mk4(vtp[tt][0], vtp[tt][1]);
      f32x4 G = {0.f, 0.f, 0.f, 0.f};
      G = mfma16k16(aw, bV, G);
      G = mfma16k16(aw, bE, G);
      const float sel = b ? G[(2*tt+1) & 3] : G[(2*tt) & 3];
      const float val = __shfl(sel, ((tt >= 2) ? 16 : 0) + r16);
      if (q == tt) outv = val;
    }
    return outv;
  };

  for (int i = blockIdx.x*4 + w; i < N; i += 2*nwaves) {
    const int iB = i + nwaves;
    const bool hasB = (iB < N);            // wave-uniform
    const int iB_s = hasB ? iB : i;

    // ---- load phase: both points' gather chains in flight together ----
    const int4 kn4a = *(const int4*)(knn + (size_t)i*16 + 4*q);
    const int4 kn4b = *(const int4*)(knn + (size_t)iB_s*16 + 4*q);
    const int jja = knn[(size_t)i*16 + r16];
    const int jjb = knn[(size_t)iB_s*16 + r16];

    uint2 vua[4], vub[4];
    const int kna[4] = {kn4a.x, kn4a.y, kn4a.z, kn4a.w};
    const int knb[4] = {kn4b.x, kn4b.y, kn4b.z, kn4b.w};
#pragma unroll
    for (int j = 0; j < 4; ++j)
      vua[j] = *(const uint2*)(v16 + (size_t)kna[j]*64 + r16*4);
#pragma unroll
    for (int j = 0; j < 4; ++j)
      vub[j] = *(const uint2*)(v16 + (size_t)knb[j]*64 + r16*4);
    u16 hvua[4], hvub[4];
#pragma unroll
    for (int j = 0; j < 4; ++j) hvua[j] = hw16[(size_t)kna[j]*8 + r16];
#pragma unroll
    for (int j = 0; j < 4; ++j) hvub[j] = hw16[(size_t)knb[j]*8 + r16];

    const float dxa = p[(size_t)jja*3]   - p[(size_t)i*3];
    const float dya = p[(size_t)jja*3+1] - p[(size_t)i*3+1];
    const float dza = p[(size_t)jja*3+2] - p[(size_t)i*3+2];
    const float dxb = p[(size_t)jjb*3]   - p[(size_t)iB_s*3];
    const float dyb = p[(size_t)jjb*3+1] - p[(size_t)iB_s*3+1];
    const float dzb = p[(size_t)jjb*3+2] - p[(size_t)iB_s*3+2];

    // ---- compute phase ----
    const float outA = computePoint(vua, hvua, dxa, dya, dza);
    mx16[(size_t)i*64 + lane] = f16b(outA);
    ssum += outA; sq = fmaf(outA, outA, sq);

    if (hasB) {
      const float outB = computePoint(vub, hvub, dxb, dyb, dzb);
      mx16[(size_t)iB*64 + lane] = f16b(outB);
      ssum += outB; sq = fmaf(outB, outB, sq);
    }
  }
  __syncthreads();
  red[w*128 + lane] = ssum; red[w*128 + 64 + lane] = sq;
  __syncthreads();
  if (t < 64) {
    const float s = red[t] + red[128+t] + red[256+t] + red[384+t];
    const float qv = red[64+t] + red[192+t] + red[320+t] + red[448+t];
    partials[(size_t)t*PST + blockIdx.x]      = s;
    partials[(size_t)(64+t)*PST + blockIdx.x] = qv;
  }
}

// ---------------------------------------------------------------------------
__global__ __launch_bounds__(256) void final_k(const u16* __restrict__ y16,
    const float* __restrict__ x, const float* __restrict__ ss,
    float* __restrict__ out, int n4)
{
  __shared__ float sl[128];
  if (threadIdx.x < 128) sl[threadIdx.x] = ss[threadIdx.x];
  __syncthreads();
  for (int idx = blockIdx.x*256 + threadIdx.x; idx < n4; idx += gridDim.x*256) {
    const int cb = (idx & 15) << 2;
    const uint2 yu = *(const uint2*)(y16 + (size_t)idx*4);
    const h2_t ylo = __builtin_bit_cast(h2_t, yu.x);
    const h2_t yhi = __builtin_bit_cast(h2_t, yu.y);
    const float4 xx = ((const float4*)x)[idx];
    float4 o;
    o.x = frelu(fmaf((float)ylo[0], sl[cb],   sl[64+cb])   + xx.x);
    o.y = frelu(fmaf((float)ylo[1], sl[cb+1], sl[64+cb+1]) + xx.y);
    o.z = frelu(fmaf((float)yhi[0], sl[cb+2], sl[64+cb+2]) + xx.z);
    o.w = frelu(fmaf((float)yhi[1], sl[cb+3], sl[64+cb+3]) + xx.w);
    ((float4*)out)[idx] = o;
  }
}

// ---------------------------------------------------------------------------
extern "C" void kernel_launch(void* const* d_in, const int* in_sizes, int n_in,
                              void* d_out, int out_size, void* d_ws, size_t ws_size,
                              hipStream_t stream)
{
  (void)n_in; (void)out_size; (void)ws_size;
  const float* p   = (const float*)d_in[0];
  const float* x   = (const float*)d_in[1];
  const int*   knn = (const int*)  d_in[2];
  const float* W1  = (const float*)d_in[3];
  const float* Wv  = (const float*)d_in[4];
  const float* Wp1 = (const float*)d_in[5];
  const float* Wp2 = (const float*)d_in[6];
  const float* Ww  = (const float*)d_in[7];
  const float* W3  = (const float*)d_in[8];
  const float* g1  = (const float*)d_in[9];
  const float* b1  = (const float*)d_in[10];
  const float* g2  = (const float*)d_in[11];
  const float* b2  = (const float*)d_in[12];
  const float* g3  = (const float*)d_in[13];
  const float* b3  = (const float*)d_in[14];
  const int N = in_sizes[0] / 3;
  const float invN = 1.f / (float)N;

  u16* ws16 = (u16*)d_ws;
  u16* y16   = ws16;                       // N*64 f16 (y1, then y3)
  u16* v16   = y16 + (size_t)N*64;         // N*64 f16 (PERMUTED col order)
  u16* mx16  = v16 + (size_t)N*64;         // N*64 f16
  u16* hw16  = mx16 + (size_t)N*64;        // N*8 f16
  uint4* fr  = (uint4*)(hw16 + (size_t)N*8);  // frag buffers (contiguous)
  uint4* wwf  = fr;                        // 128 uint4
  uint4* wp2f = fr + 128;                  // 512 uint4
  uint4* w1f  = fr + 640;                  // 384 uint4
  float* partials = (float*)(fr + 1024);   // 128*PST f32
  float* ss1      = partials + (size_t)128*PST;
  float* ss2      = ss1 + 128;
  float* ss3      = ss2 + 128;

  gemm_mfma_k<0, false><<<GRID_GEMM + 1, 256, 0, stream>>>(
      x, W1, Ww, nullptr, y16, nullptr, partials, N, Wp2, Wp1, wwf, wp2f, w1f);
  fin_k<<<64, 256, 0, stream>>>(partials, GRID_GEMM, g1, b1, ss1, invN);
  gemm_mfma_k<1, true><<<GRID_GEMM, 256, 0, stream>>>(
      y16, Wv, Ww, ss1, v16, hw16, nullptr, N, nullptr, nullptr, nullptr, nullptr, nullptr);
  mixer_k<<<GRID_MIX, 256, 0, stream>>>(p, knn, v16, hw16, fr, mx16, partials, N);
  fin_k<<<64, 256, 0, stream>>>(partials, GRID_MIX, g2, b2, ss2, invN);
  gemm_mfma_k<2, true><<<GRID_GEMM, 256, 0, stream>>>(
      mx16, W3, nullptr, ss2, y16, nullptr, partials, N, nullptr, nullptr, nullptr, nullptr, nullptr);
  fin_k<<<64, 256, 0, stream>>>(partials, GRID_GEMM, g3, b3, ss3, invN);
  final_k<<<GRID_ELT, 256, 0, stream>>>(y16, x, ss3, (float*)d_out, N*16);
}